// Round 1
// baseline (460.825 us; speedup 1.0000x reference)
//
#include <hip/hip_runtime.h>
#include <math.h>

#define N_ATOMS 4096
#define F 128
#define K 8
#define KF 1024           // K*F
#define KFF 131072        // K*F*F
#define FF 16384          // F*F
#define NF 524288         // N*F
#define NKF 4194304       // N*K*F
#define MAXNB 128
#define RMAX 5.0f
#define GAMMA 2.56f       // (K/RMAX)^2
#define MU_STEP 0.714285714285714f  // RMAX/(K-1)
#define PI_F 3.14159265358979323846f
#define POR (PI_F / RMAX)

// ---------------- neighbor list (deterministic ballot compaction) -----------
__global__ __launch_bounds__(64) void k_nb(const float* __restrict__ pos,
        int* __restrict__ nb_idx, float* __restrict__ nb_d, int* __restrict__ nb_cnt){
  int i = blockIdx.x;
  int lane = threadIdx.x;
  float pix = pos[3*i], piy = pos[3*i+1], piz = pos[3*i+2];
  float sqi = pix*pix + piy*piy + piz*piz;
  int count = 0;
  for (int jb = 0; jb < N_ATOMS; jb += 64){
    int j = jb + lane;
    float pjx = pos[3*j], pjy = pos[3*j+1], pjz = pos[3*j+2];
    float sqj = pjx*pjx + pjy*pjy + pjz*pjz;
    float dot = pix*pjx + piy*pjy + piz*pjz;
    float d2 = sqi + sqj - 2.0f*dot;
    float d = sqrtf(d2);
    bool pred = (j != i) && (d2 > 0.0f) && (d < RMAX);
    unsigned long long m = __ballot(pred);
    int off = __popcll(m & ((1ull << lane) - 1ull));
    if (pred){
      int p = count + off;
      if (p < MAXNB){ nb_idx[i*MAXNB + p] = j; nb_d[i*MAXNB + p] = d; }
    }
    count += __popcll(m);
  }
  if (lane == 0) nb_cnt[i] = count > MAXNB ? MAXNB : count;
}

// ---------------- h0 = embed[z] ---------------------------------------------
__global__ __launch_bounds__(256) void k_embed(const int* __restrict__ z,
        const float* __restrict__ embed, float* __restrict__ h0){
  int idx = blockIdx.x*256 + threadIdx.x;   // N*F total
  int i = idx >> 7, f = idx & 127;
  h0[idx] = embed[z[i]*F + f];
}

// ---------------- weight transposes (for coalesced backward) ----------------
// WT[g*KF + k*F + f] = W[k*FF + f*F + g];  Wr1T[f*F+g] = Wr1[g*F+f]
__global__ __launch_bounds__(256) void k_transpose(const float* __restrict__ W1,
        const float* __restrict__ W2, const float* __restrict__ Wr1,
        float* __restrict__ WT1, float* __restrict__ WT2, float* __restrict__ Wr1T){
  int idx = blockIdx.x*256 + threadIdx.x;
  if (idx < KFF){
    int g = idx >> 10, kf = idx & 1023;
    int k = kf >> 7, f = kf & 127;
    WT1[idx] = W1[k*FF + f*F + g];
    WT2[idx] = W2[k*FF + f*F + g];
  }
  if (idx < FF){
    int f = idx >> 7, g = idx & 127;
    Wr1T[idx] = Wr1[g*F + f];
  }
}

// ---------------- A[i,k,f] = sum_j rbf_k(d_ij) * h[j,f] ---------------------
__global__ __launch_bounds__(256) void k_agg(const float* __restrict__ h_in,
        const int* __restrict__ nb_idx, const float* __restrict__ nb_d,
        const int* __restrict__ nb_cnt, float* __restrict__ A){
  int i = blockIdx.x;
  int t = threadIdx.x;
  int f = t & 127;
  int kq = (t >> 7) * 4;
  __shared__ float s_rbf[8][8];
  __shared__ int s_j[8];
  float a0=0.f, a1=0.f, a2=0.f, a3=0.f;
  int cnt = nb_cnt[i];
  for (int base = 0; base < cnt; base += 8){
    __syncthreads();
    if (t < 64){
      int u = t >> 3, k = t & 7;
      int n = base + u;
      float r = 0.0f;
      if (n < cnt){
        float d = nb_d[i*MAXNB + n];
        float env = 0.5f*(cosf(POR*d) + 1.0f);
        float dm = d - MU_STEP*(float)k;
        r = expf(-GAMMA*dm*dm)*env;
        if (k == 0) s_j[u] = nb_idx[i*MAXNB + n];
      } else if (k == 0) s_j[u] = 0;
      s_rbf[u][k] = r;
    }
    __syncthreads();
    #pragma unroll
    for (int u = 0; u < 8; u++){
      float hv = h_in[s_j[u]*F + f];
      a0 += s_rbf[u][kq+0]*hv;
      a1 += s_rbf[u][kq+1]*hv;
      a2 += s_rbf[u][kq+2]*hv;
      a3 += s_rbf[u][kq+3]*hv;
    }
  }
  A[i*KF + (kq+0)*F + f] = a0;
  A[i*KF + (kq+1)*F + f] = a1;
  A[i*KF + (kq+2)*F + f] = a2;
  A[i*KF + (kq+3)*F + f] = a3;
}

// ---------------- m = A.W + h_in; h_out = silu(m) ---------------------------
__global__ __launch_bounds__(128) void k_mmfwd(const float* __restrict__ A,
        const float* __restrict__ W, const float* __restrict__ h_in,
        float* __restrict__ m_out, float* __restrict__ h_out){
  int a0 = blockIdx.x * 8;
  int g = threadIdx.x;
  __shared__ float sA[8][KF];   // 32 KB
  for (int idx = threadIdx.x; idx < 8*KF; idx += 128)
    sA[idx >> 10][idx & 1023] = A[a0*KF + idx];
  __syncthreads();
  float acc[8] = {0,0,0,0,0,0,0,0};
  #pragma unroll 4
  for (int kf = 0; kf < KF; kf++){
    float w = W[kf*F + g];
    #pragma unroll
    for (int r = 0; r < 8; r++) acc[r] += sA[r][kf]*w;
  }
  for (int r = 0; r < 8; r++){
    int i = a0 + r;
    float m = acc[r] + h_in[i*F + g];
    m_out[i*F + g] = m;
    float s = 1.0f/(1.0f + expf(-m));
    h_out[i*F + g] = m*s;
  }
}

// ---------------- dA[i,kf] = sum_g gbuf[i,g]*WT[g,kf] -----------------------
__global__ __launch_bounds__(256) void k_mmbwd(const float* __restrict__ gbuf,
        const float* __restrict__ WT, float* __restrict__ dA){
  int a0 = blockIdx.x * 4;
  int t = threadIdx.x;
  __shared__ float sg[4][F];
  for (int idx = t; idx < 4*F; idx += 256) sg[idx >> 7][idx & 127] = gbuf[a0*F + idx];
  __syncthreads();
  float acc[4][4] = {{0}};
  int kf0 = t*4;
  for (int g = 0; g < F; g++){
    const float4 w = *reinterpret_cast<const float4*>(&WT[g*KF + kf0]);
    #pragma unroll
    for (int r = 0; r < 4; r++){
      float gv = sg[r][g];
      acc[r][0] += gv*w.x; acc[r][1] += gv*w.y; acc[r][2] += gv*w.z; acc[r][3] += gv*w.w;
    }
  }
  for (int r = 0; r < 4; r++){
    float4 o = {acc[r][0], acc[r][1], acc[r][2], acc[r][3]};
    *reinterpret_cast<float4*>(&dA[(a0+r)*KF + kf0]) = o;
  }
}

// ---------------- readout fwd + bwd: e_atom, g2 = dE/dm2 --------------------
__global__ __launch_bounds__(128) void k_readout(const float* __restrict__ h2,
        const float* __restrict__ m2, const float* __restrict__ Wr1,
        const float* __restrict__ Wr1T, const float* __restrict__ Wr2,
        float* __restrict__ e_at, float* __restrict__ g2){
  int i = blockIdx.x;
  int t = threadIdx.x;
  __shared__ float sh[F];
  __shared__ float sdu[F];
  __shared__ float red[F];
  sh[t] = h2[i*F + t];
  __syncthreads();
  float u = 0.f;
  for (int g = 0; g < F; g++) u += sh[g]*Wr1[g*F + t];
  float sig = 1.0f/(1.0f + expf(-u));
  float s = u*sig;
  float w2 = Wr2[t];
  red[t] = s*w2;
  __syncthreads();
  for (int o = 64; o > 0; o >>= 1){ if (t < o) red[t] += red[t+o]; __syncthreads(); }
  if (t == 0) e_at[i] = red[0];
  float dsilu_u = sig*(1.0f + u*(1.0f - sig));
  sdu[t] = w2*dsilu_u;
  __syncthreads();
  float dh2 = 0.f;
  for (int f = 0; f < F; f++) dh2 += sdu[f]*Wr1T[f*F + t];
  float mm = m2[i*F + t];
  float sg = 1.0f/(1.0f + expf(-mm));
  g2[i*F + t] = dh2*(sg*(1.0f + mm*(1.0f - sg)));
}

// ---------------- deterministic energy sum ----------------------------------
__global__ __launch_bounds__(256) void k_esum(const float* __restrict__ e_at,
        float* __restrict__ out){
  __shared__ float red[256];
  float s = 0.f;
  for (int i = threadIdx.x; i < N_ATOMS; i += 256) s += e_at[i];
  red[threadIdx.x] = s;
  __syncthreads();
  for (int o = 128; o > 0; o >>= 1){
    if (threadIdx.x < o) red[threadIdx.x] += red[threadIdx.x + o];
    __syncthreads();
  }
  if (threadIdx.x == 0) out[0] = red[0];
}

// ------- g1[j,f] = (g2[j,f] + sum_{i in nb(j)} sum_k rbf_k dA2[i,k,f]) * silu'(m1)
__global__ __launch_bounds__(128) void k_dh1(const float* __restrict__ dA2,
        const float* __restrict__ g2, const float* __restrict__ m1,
        const int* __restrict__ nb_idx, const float* __restrict__ nb_d,
        const int* __restrict__ nb_cnt, float* __restrict__ g1){
  int j = blockIdx.x;
  int f = threadIdx.x;
  __shared__ float s_rbf[8][8];
  __shared__ int s_i[8];
  float acc = g2[j*F + f];
  int cnt = nb_cnt[j];
  for (int base = 0; base < cnt; base += 8){
    __syncthreads();
    if (f < 64){
      int u = f >> 3, k = f & 7;
      int n = base + u;
      float r = 0.0f;
      if (n < cnt){
        float d = nb_d[j*MAXNB + n];
        float env = 0.5f*(cosf(POR*d) + 1.0f);
        float dm = d - MU_STEP*(float)k;
        r = expf(-GAMMA*dm*dm)*env;
        if (k == 0) s_i[u] = nb_idx[j*MAXNB + n];
      } else if (k == 0) s_i[u] = 0;
      s_rbf[u][k] = r;
    }
    __syncthreads();
    for (int u = 0; u < 8; u++){
      const float* row = &dA2[s_i[u]*KF];
      #pragma unroll
      for (int k = 0; k < 8; k++) acc += s_rbf[u][k]*row[k*F + f];
    }
  }
  float mm = m1[j*F + f];
  float sg = 1.0f/(1.0f + expf(-mm));
  g1[j*F + f] = acc*(sg*(1.0f + mm*(1.0f - sg)));
}

// ------- per-edge scalar: dE/dd(i->j) ---------------------------------------
__global__ __launch_bounds__(256) void k_edge(const float* __restrict__ dA1,
        const float* __restrict__ dA2, const float* __restrict__ h0,
        const float* __restrict__ h1,
        const int* __restrict__ nb_idx, const float* __restrict__ nb_d,
        const int* __restrict__ nb_cnt, float* __restrict__ edge_s){
  int i = blockIdx.x;
  int t = threadIdx.x;
  int lane = t & 63, w = t >> 6;
  __shared__ float sA1[KF], sA2[KF];
  for (int idx = t; idx < KF; idx += 256){
    sA1[idx] = dA1[i*KF + idx];
    sA2[idx] = dA2[i*KF + idx];
  }
  __syncthreads();
  int cnt = nb_cnt[i];
  for (int n = w; n < cnt; n += 4){
    int j = nb_idx[i*MAXNB + n];
    float d = nb_d[i*MAXNB + n];
    float env = 0.5f*(cosf(POR*d) + 1.0f);
    float denv = -0.5f*POR*sinf(POR*d);
    float dr[8];
    #pragma unroll
    for (int k = 0; k < 8; k++){
      float dm = d - MU_STEP*(float)k;
      float G = expf(-GAMMA*dm*dm);
      dr[k] = G*(-2.0f*GAMMA*dm)*env + G*denv;
    }
    float part = 0.f;
    #pragma unroll
    for (int hh = 0; hh < 2; hh++){
      int f = lane + 64*hh;
      float c2 = 0.f, c1 = 0.f;
      #pragma unroll
      for (int k = 0; k < 8; k++){ c2 += dr[k]*sA2[k*F + f]; c1 += dr[k]*sA1[k*F + f]; }
      part += c2*h1[j*F + f] + c1*h0[j*F + f];
    }
    #pragma unroll
    for (int o = 1; o < 64; o <<= 1) part += __shfl_xor(part, o);
    if (lane == 0) edge_s[i*MAXNB + n] = part;
  }
}

// ------- force: F_a = -sum_j (s_aj + s_ja) * (pa-pj)/d ----------------------
__global__ __launch_bounds__(64) void k_force(const float* __restrict__ pos,
        const int* __restrict__ nb_idx, const float* __restrict__ nb_d,
        const int* __restrict__ nb_cnt, const float* __restrict__ edge_s,
        float* __restrict__ out){
  int a = blockIdx.x;
  int lane = threadIdx.x;
  float pax = pos[3*a], pay = pos[3*a+1], paz = pos[3*a+2];
  int cnt = nb_cnt[a];
  float fx = 0.f, fy = 0.f, fz = 0.f;
  for (int n = lane; n < cnt; n += 64){
    int j = nb_idx[a*MAXNB + n];
    float d = nb_d[a*MAXNB + n];
    float s = edge_s[a*MAXNB + n];
    // binary search for a in j's sorted neighbor list
    int cj = nb_cnt[j];
    int lo = 0, hi = cj - 1, p = -1;
    while (lo <= hi){
      int mid = (lo + hi) >> 1;
      int v = nb_idx[j*MAXNB + mid];
      if (v == a){ p = mid; break; }
      if (v < a) lo = mid + 1; else hi = mid - 1;
    }
    float sj = (p >= 0) ? edge_s[j*MAXNB + p] : 0.0f;
    float coef = (s + sj)/d;
    float dx = pax - pos[3*j], dy = pay - pos[3*j+1], dz = paz - pos[3*j+2];
    fx -= coef*dx; fy -= coef*dy; fz -= coef*dz;
  }
  #pragma unroll
  for (int o = 1; o < 64; o <<= 1){
    fx += __shfl_xor(fx, o); fy += __shfl_xor(fy, o); fz += __shfl_xor(fz, o);
  }
  if (lane == 0){
    out[1 + 3*a + 0] = fx;
    out[1 + 3*a + 1] = fy;
    out[1 + 3*a + 2] = fz;
  }
}

extern "C" void kernel_launch(void* const* d_in, const int* in_sizes, int n_in,
                              void* d_out, int out_size, void* d_ws, size_t ws_size,
                              hipStream_t stream){
  const float* pos   = (const float*)d_in[0];
  const int*   z     = (const int*)  d_in[1];
  const float* embed = (const float*)d_in[2];
  const float* W1    = (const float*)d_in[3];
  const float* W2    = (const float*)d_in[4];
  const float* Wr1   = (const float*)d_in[5];
  const float* Wr2   = (const float*)d_in[6];
  float* out = (float*)d_out;

  float* ws = (float*)d_ws;
  float* h0   = ws;            // NF
  float* h1   = h0 + NF;
  float* h2   = h1 + NF;
  float* m1   = h2 + NF;
  float* m2   = m1 + NF;
  float* g2b  = m2 + NF;
  float* g1b  = g2b + NF;
  float* Abuf = g1b + NF;      // NKF  (A fwd, then reused as dA2)
  float* dA1  = Abuf + NKF;    // NKF
  float* WT1  = dA1 + NKF;     // KFF
  float* WT2  = WT1 + KFF;     // KFF
  float* Wr1T = WT2 + KFF;     // FF
  float* e_at = Wr1T + FF;     // N
  float* nb_d = e_at + N_ATOMS;        // N*MAXNB
  float* edge_s = nb_d + N_ATOMS*MAXNB;// N*MAXNB
  int* nb_idx = (int*)(edge_s + N_ATOMS*MAXNB); // N*MAXNB
  int* nb_cnt = nb_idx + N_ATOMS*MAXNB;         // N

  k_nb<<<N_ATOMS, 64, 0, stream>>>(pos, nb_idx, nb_d, nb_cnt);
  k_embed<<<NF/256, 256, 0, stream>>>(z, embed, h0);
  k_transpose<<<KFF/256, 256, 0, stream>>>(W1, W2, Wr1, WT1, WT2, Wr1T);

  // layer 1
  k_agg<<<N_ATOMS, 256, 0, stream>>>(h0, nb_idx, nb_d, nb_cnt, Abuf);
  k_mmfwd<<<N_ATOMS/8, 128, 0, stream>>>(Abuf, W1, h0, m1, h1);
  // layer 2
  k_agg<<<N_ATOMS, 256, 0, stream>>>(h1, nb_idx, nb_d, nb_cnt, Abuf);
  k_mmfwd<<<N_ATOMS/8, 128, 0, stream>>>(Abuf, W2, h1, m2, h2);

  // readout + energy
  k_readout<<<N_ATOMS, 128, 0, stream>>>(h2, m2, Wr1, Wr1T, Wr2, e_at, g2b);
  k_esum<<<1, 256, 0, stream>>>(e_at, out);

  // backward
  k_mmbwd<<<N_ATOMS/4, 256, 0, stream>>>(g2b, WT2, Abuf);           // dA2 into Abuf
  k_dh1<<<N_ATOMS, 128, 0, stream>>>(Abuf, g2b, m1, nb_idx, nb_d, nb_cnt, g1b);
  k_mmbwd<<<N_ATOMS/4, 256, 0, stream>>>(g1b, WT1, dA1);
  k_edge<<<N_ATOMS, 256, 0, stream>>>(dA1, Abuf, h0, h1, nb_idx, nb_d, nb_cnt, edge_s);
  k_force<<<N_ATOMS, 64, 0, stream>>>(pos, nb_idx, nb_d, nb_cnt, edge_s, out);
}

// Round 3
// 378.757 us; speedup vs baseline: 1.2167x; 1.2167x over previous
//
#include <hip/hip_runtime.h>
#include <math.h>

#define N_ATOMS 4096
#define F 128
#define K 8
#define KF 1024           // K*F
#define KFF 131072        // K*F*F
#define FF 16384          // F*F
#define NF 524288         // N*F
#define NKF 4194304       // N*K*F
#define MAXNB 128
#define RMAX 5.0f
#define GAMMA 2.56f       // (K/RMAX)^2
#define MU_STEP 0.714285714285714f  // RMAX/(K-1)
#define PI_F 3.14159265358979323846f
#define POR (PI_F / RMAX)

__device__ __forceinline__ float sigm(float x){ return 1.0f/(1.0f + expf(-x)); }

// ---------------- neighbor list (deterministic ballot compaction) -----------
__global__ __launch_bounds__(64) void k_nb(const float* __restrict__ pos,
        int* __restrict__ nb_idx, float* __restrict__ nb_d, int* __restrict__ nb_cnt){
  int i = blockIdx.x;
  int lane = threadIdx.x;
  float pix = pos[3*i], piy = pos[3*i+1], piz = pos[3*i+2];
  float sqi = pix*pix + piy*piy + piz*piz;
  int count = 0;
  for (int jb = 0; jb < N_ATOMS; jb += 64){
    int j = jb + lane;
    float pjx = pos[3*j], pjy = pos[3*j+1], pjz = pos[3*j+2];
    float sqj = pjx*pjx + pjy*pjy + pjz*pjz;
    float dot = pix*pjx + piy*pjy + piz*pjz;
    float d2 = sqi + sqj - 2.0f*dot;
    float d = sqrtf(d2);
    bool pred = (j != i) && (d2 > 0.0f) && (d < RMAX);
    unsigned long long m = __ballot(pred);
    int off = __popcll(m & ((1ull << lane) - 1ull));
    if (pred){
      int p = count + off;
      if (p < MAXNB){ nb_idx[i*MAXNB + p] = j; nb_d[i*MAXNB + p] = d; }
    }
    count += __popcll(m);
  }
  if (lane == 0) nb_cnt[i] = count > MAXNB ? MAXNB : count;
}

// ---------------- h0 = embed[z] ---------------------------------------------
__global__ __launch_bounds__(256) void k_embed(const int* __restrict__ z,
        const float* __restrict__ embed, float* __restrict__ h0){
  int idx = blockIdx.x*256 + threadIdx.x;
  int i = idx >> 7, f = idx & 127;
  h0[idx] = embed[z[i]*F + f];
}

// ---------------- weight transposes -----------------------------------------
// WT[g*KF + k*F + f]   = W[k,f,g]   (for dA = g @ WT)
// WD2[(k*F+g)*F + f]   = W2[k,f,g]  (for dh1 = Agg2 @ WD2)
// Wr1T[f*F + g]        = Wr1[g,f]
__global__ __launch_bounds__(256) void k_wprep(const float* __restrict__ W1,
        const float* __restrict__ W2, const float* __restrict__ Wr1,
        float* __restrict__ WT1, float* __restrict__ WT2,
        float* __restrict__ WD2, float* __restrict__ Wr1T){
  int idx = blockIdx.x*256 + threadIdx.x;
  {
    int g = idx >> 10, kf = idx & 1023;
    int k = kf >> 7, f = kf & 127;
    WT1[idx] = W1[k*FF + f*F + g];
    WT2[idx] = W2[k*FF + f*F + g];
  }
  {
    int k = idx >> 14, g = (idx >> 7) & 127, f = idx & 127;
    WD2[idx] = W2[k*FF + f*F + g];
  }
  if (idx < FF){
    int f = idx >> 7, g = idx & 127;
    Wr1T[idx] = Wr1[g*F + f];
  }
}

// ---------------- A[a,k,f] = sum_n rbf_k(d_an) * h[j_n,f] -------------------
__global__ __launch_bounds__(256) void k_agg(const float* __restrict__ h_in,
        const int* __restrict__ nb_idx, const float* __restrict__ nb_d,
        const int* __restrict__ nb_cnt, float* __restrict__ A){
  int a = blockIdx.x;
  int t = threadIdx.x;
  int f = t & 127;
  int kq = (t >> 7) * 4;
  __shared__ float s_rbf[MAXNB][8];
  __shared__ int s_j[MAXNB];
  int cnt = nb_cnt[a];
  for (int idx = t; idx < cnt*8; idx += 256){
    int n = idx >> 3, k = idx & 7;
    float d = nb_d[a*MAXNB + n];
    float dm = d - MU_STEP*(float)k;
    float env = 0.5f*(cosf(POR*d) + 1.0f);
    s_rbf[n][k] = expf(-GAMMA*dm*dm)*env;
  }
  for (int idx = t; idx < cnt; idx += 256) s_j[idx] = nb_idx[a*MAXNB + idx];
  __syncthreads();
  float a0=0.f, a1=0.f, a2=0.f, a3=0.f;
  int n = 0;
  for (; n + 2 <= cnt; n += 2){
    float hv0 = h_in[s_j[n]*F + f];
    float hv1 = h_in[s_j[n+1]*F + f];
    float4 r0 = *(const float4*)&s_rbf[n][kq];
    float4 r1 = *(const float4*)&s_rbf[n+1][kq];
    a0 += r0.x*hv0 + r1.x*hv1;
    a1 += r0.y*hv0 + r1.y*hv1;
    a2 += r0.z*hv0 + r1.z*hv1;
    a3 += r0.w*hv0 + r1.w*hv1;
  }
  if (n < cnt){
    float hv0 = h_in[s_j[n]*F + f];
    float4 r0 = *(const float4*)&s_rbf[n][kq];
    a0 += r0.x*hv0; a1 += r0.y*hv0; a2 += r0.z*hv0; a3 += r0.w*hv0;
  }
  A[a*KF + (kq+0)*F + f] = a0;
  A[a*KF + (kq+1)*F + f] = a1;
  A[a*KF + (kq+2)*F + f] = a2;
  A[a*KF + (kq+3)*F + f] = a3;
}

// ------- GEMM fwd: out[i,g] = sum_kf A[i,kf] W[kf,g] (+epilogue) ------------
// tile 16 rows x 128 cols, 256 thr, double-buffered LDS, reg-prefetch.
// mode 0: m = acc + addv; out_m = m; out_h = silu(m)
// mode 1: out_h = (acc + addv) * silu'(msrc)
#define FMA4(acc, s, vv) { (acc).x += (s)*(vv).x; (acc).y += (s)*(vv).y; (acc).z += (s)*(vv).z; (acc).w += (s)*(vv).w; }
__global__ __launch_bounds__(256) void k_gemm_fwd(const float* __restrict__ A,
        const float* __restrict__ W, const float* __restrict__ addv,
        const float* __restrict__ msrc, float* __restrict__ out_m,
        float* __restrict__ out_h, int mode){
  __shared__ float sA[2][16*64];
  __shared__ float sW[2][64*128];
  int t = threadIdx.x;
  int rb = blockIdx.x * 16;
  int c4 = t & 31, rg = t >> 5;
  int r0 = rg*2;
  const float4* Asrc = (const float4*)(A + (rb + (t>>4))*1024) + (t & 15);
  const float4* Wsrc = (const float4*)W;
  float4 ra; float4 rw[8];
  // prologue: chunk 0
  ra = Asrc[0];
  #pragma unroll
  for (int s = 0; s < 8; s++) rw[s] = Wsrc[t + s*256];
  ((float4*)sA[0])[t] = ra;
  #pragma unroll
  for (int s = 0; s < 8; s++) ((float4*)sW[0])[t + s*256] = rw[s];
  __syncthreads();
  float4 acc0 = {0,0,0,0}, acc1 = {0,0,0,0};
  int cur = 0;
  for (int ch = 0; ch < 16; ch++){
    if (ch < 15){
      ra = Asrc[(ch+1)*16];
      #pragma unroll
      for (int s = 0; s < 8; s++) rw[s] = Wsrc[(ch+1)*2048 + t + s*256];
    }
    const float* cA = sA[cur];
    const float* cW = sW[cur];
    #pragma unroll
    for (int kq = 0; kq < 16; kq++){
      float4 a0 = *(const float4*)&cA[r0*64 + kq*4];
      float4 a1 = *(const float4*)&cA[(r0+1)*64 + kq*4];
      float4 w0 = *(const float4*)&cW[(kq*4+0)*128 + c4*4];
      float4 w1 = *(const float4*)&cW[(kq*4+1)*128 + c4*4];
      float4 w2 = *(const float4*)&cW[(kq*4+2)*128 + c4*4];
      float4 w3 = *(const float4*)&cW[(kq*4+3)*128 + c4*4];
      FMA4(acc0, a0.x, w0) FMA4(acc0, a0.y, w1) FMA4(acc0, a0.z, w2) FMA4(acc0, a0.w, w3)
      FMA4(acc1, a1.x, w0) FMA4(acc1, a1.y, w1) FMA4(acc1, a1.z, w2) FMA4(acc1, a1.w, w3)
    }
    if (ch < 15){
      ((float4*)sA[cur^1])[t] = ra;
      #pragma unroll
      for (int s = 0; s < 8; s++) ((float4*)sW[cur^1])[t + s*256] = rw[s];
    }
    __syncthreads();
    cur ^= 1;
  }
  int i0 = rb + r0, i1 = i0 + 1, cc = c4*4;
  if (mode == 0){
    float4 hv0 = *(const float4*)&addv[i0*F + cc];
    float4 hv1 = *(const float4*)&addv[i1*F + cc];
    float4 m0, m1v, o0, o1;
    m0.x = acc0.x + hv0.x; m0.y = acc0.y + hv0.y; m0.z = acc0.z + hv0.z; m0.w = acc0.w + hv0.w;
    m1v.x = acc1.x + hv1.x; m1v.y = acc1.y + hv1.y; m1v.z = acc1.z + hv1.z; m1v.w = acc1.w + hv1.w;
    *(float4*)&out_m[i0*F + cc] = m0;
    *(float4*)&out_m[i1*F + cc] = m1v;
    o0.x = m0.x*sigm(m0.x); o0.y = m0.y*sigm(m0.y); o0.z = m0.z*sigm(m0.z); o0.w = m0.w*sigm(m0.w);
    o1.x = m1v.x*sigm(m1v.x); o1.y = m1v.y*sigm(m1v.y); o1.z = m1v.z*sigm(m1v.z); o1.w = m1v.w*sigm(m1v.w);
    *(float4*)&out_h[i0*F + cc] = o0;
    *(float4*)&out_h[i1*F + cc] = o1;
  } else {
    float4 gv0 = *(const float4*)&addv[i0*F + cc];
    float4 gv1 = *(const float4*)&addv[i1*F + cc];
    float4 mm0 = *(const float4*)&msrc[i0*F + cc];
    float4 mm1 = *(const float4*)&msrc[i1*F + cc];
    float4 o0, o1;
    float s;
    s = sigm(mm0.x); o0.x = (acc0.x+gv0.x)*(s*(1.f+mm0.x*(1.f-s)));
    s = sigm(mm0.y); o0.y = (acc0.y+gv0.y)*(s*(1.f+mm0.y*(1.f-s)));
    s = sigm(mm0.z); o0.z = (acc0.z+gv0.z)*(s*(1.f+mm0.z*(1.f-s)));
    s = sigm(mm0.w); o0.w = (acc0.w+gv0.w)*(s*(1.f+mm0.w*(1.f-s)));
    s = sigm(mm1.x); o1.x = (acc1.x+gv1.x)*(s*(1.f+mm1.x*(1.f-s)));
    s = sigm(mm1.y); o1.y = (acc1.y+gv1.y)*(s*(1.f+mm1.y*(1.f-s)));
    s = sigm(mm1.z); o1.z = (acc1.z+gv1.z)*(s*(1.f+mm1.z*(1.f-s)));
    s = sigm(mm1.w); o1.w = (acc1.w+gv1.w)*(s*(1.f+mm1.w*(1.f-s)));
    *(float4*)&out_h[i0*F + cc] = o0;
    *(float4*)&out_h[i1*F + cc] = o1;
  }
}

// ------- GEMM bwd: dA[i,kf] = sum_g G[i,g] WT[g,kf] -------------------------
// tile 16 rows x 256 cols (grid.y = 4 col slices), 256 thr.
__global__ __launch_bounds__(256) void k_gemm_bwd(const float* __restrict__ G,
        const float* __restrict__ WT, float* __restrict__ dA){
  __shared__ float sg[16*128];
  __shared__ float sW[32*256];
  int t = threadIdx.x;
  int rb = blockIdx.x * 16;
  int nb0 = blockIdx.y * 256;
  int c4 = t & 31, rg = t >> 5;
  int r0 = rg*2;
  {
    const float4* src = (const float4*)(G + rb*128);
    float4* dst = (float4*)sg;
    dst[t] = src[t];
    dst[t+256] = src[t+256];
  }
  float4 accA0 = {0,0,0,0}, accB0 = {0,0,0,0};  // row r0: quads c4, c4+32
  float4 accA1 = {0,0,0,0}, accB1 = {0,0,0,0};  // row r0+1
  for (int kc = 0; kc < 4; kc++){
    __syncthreads();
    {
      const float4* wsrc = (const float4*)(WT + (kc*32)*1024 + nb0);
      float4* wdst = (float4*)sW;
      #pragma unroll
      for (int s = 0; s < 8; s++){
        int f4 = t + s*256;
        wdst[f4] = wsrc[(f4 >> 6)*256 + (f4 & 63)];
      }
    }
    __syncthreads();
    #pragma unroll 8
    for (int k = 0; k < 32; k++){
      float a0 = sg[r0*128 + kc*32 + k];
      float a1 = sg[(r0+1)*128 + kc*32 + k];
      float4 w0 = *(const float4*)&sW[k*256 + c4*4];
      float4 w1 = *(const float4*)&sW[k*256 + 128 + c4*4];
      FMA4(accA0, a0, w0) FMA4(accB0, a0, w1)
      FMA4(accA1, a1, w0) FMA4(accB1, a1, w1)
    }
  }
  *(float4*)&dA[(rb+r0)*1024 + nb0 + c4*4]        = accA0;
  *(float4*)&dA[(rb+r0)*1024 + nb0 + 128 + c4*4]  = accB0;
  *(float4*)&dA[(rb+r0+1)*1024 + nb0 + c4*4]      = accA1;
  *(float4*)&dA[(rb+r0+1)*1024 + nb0 + 128 + c4*4] = accB1;
}

// ---------------- readout fwd + bwd: e_atom, g2 = dE/dm2 --------------------
__global__ __launch_bounds__(128) void k_readout(const float* __restrict__ h2,
        const float* __restrict__ m2, const float* __restrict__ Wr1,
        const float* __restrict__ Wr1T, const float* __restrict__ Wr2,
        float* __restrict__ e_at, float* __restrict__ g2){
  int b = blockIdx.x * 8;
  int t = threadIdx.x;
  int lane = t & 63, wv = t >> 6;
  __shared__ float sh[128][8];
  __shared__ float sdu[128][8];
  __shared__ float red[2][8];
  #pragma unroll
  for (int r = 0; r < 8; r++) sh[t][r] = h2[(b+r)*F + t];
  __syncthreads();
  float u[8] = {0,0,0,0,0,0,0,0};
  for (int g = 0; g < 128; g++){
    float wvv = Wr1[g*F + t];
    float4 s0 = *(const float4*)&sh[g][0];
    float4 s1 = *(const float4*)&sh[g][4];
    u[0] += s0.x*wvv; u[1] += s0.y*wvv; u[2] += s0.z*wvv; u[3] += s0.w*wvv;
    u[4] += s1.x*wvv; u[5] += s1.y*wvv; u[6] += s1.z*wvv; u[7] += s1.w*wvv;
  }
  float w2 = Wr2[t];
  #pragma unroll
  for (int r = 0; r < 8; r++){
    float sg = sigm(u[r]);
    float e = u[r]*sg*w2;
    #pragma unroll
    for (int o = 1; o < 64; o <<= 1) e += __shfl_xor(e, o);
    if (lane == 0) red[wv][r] = e;
    sdu[t][r] = w2*(sg*(1.f + u[r]*(1.f - sg)));
  }
  __syncthreads();
  if (t < 8) e_at[b+t] = red[0][t] + red[1][t];
  float dh[8] = {0,0,0,0,0,0,0,0};
  for (int f = 0; f < 128; f++){
    float wvv = Wr1T[f*F + t];
    float4 s0 = *(const float4*)&sdu[f][0];
    float4 s1 = *(const float4*)&sdu[f][4];
    dh[0] += s0.x*wvv; dh[1] += s0.y*wvv; dh[2] += s0.z*wvv; dh[3] += s0.w*wvv;
    dh[4] += s1.x*wvv; dh[5] += s1.y*wvv; dh[6] += s1.z*wvv; dh[7] += s1.w*wvv;
  }
  #pragma unroll
  for (int r = 0; r < 8; r++){
    float mm = m2[(b+r)*F + t];
    float sg = sigm(mm);
    g2[(b+r)*F + t] = dh[r]*(sg*(1.f + mm*(1.f - sg)));
  }
}

// ---------------- deterministic energy sum ----------------------------------
__global__ __launch_bounds__(256) void k_esum(const float* __restrict__ e_at,
        float* __restrict__ out){
  __shared__ float red[256];
  float s = 0.f;
  for (int i = threadIdx.x; i < N_ATOMS; i += 256) s += e_at[i];
  red[threadIdx.x] = s;
  __syncthreads();
  for (int o = 128; o > 0; o >>= 1){
    if (threadIdx.x < o) red[threadIdx.x] += red[threadIdx.x + o];
    __syncthreads();
  }
  if (threadIdx.x == 0) out[0] = red[0];
}

// ------- per-edge scalar: dE/dd(a->j) ---------------------------------------
__global__ __launch_bounds__(256) void k_edge(const float* __restrict__ dA1,
        const float* __restrict__ dA2, const float* __restrict__ h0,
        const float* __restrict__ h1,
        const int* __restrict__ nb_idx, const float* __restrict__ nb_d,
        const int* __restrict__ nb_cnt, float* __restrict__ edge_s){
  int a = blockIdx.x;
  int t = threadIdx.x;
  int lane = t & 63, w = t >> 6;
  __shared__ float sdr[MAXNB][8];
  __shared__ int s_j[MAXNB];
  int cnt = nb_cnt[a];
  for (int idx = t; idx < cnt*8; idx += 256){
    int n = idx >> 3, k = idx & 7;
    float d = nb_d[a*MAXNB + n];
    float dm = d - MU_STEP*(float)k;
    float G = expf(-GAMMA*dm*dm);
    float ph = POR*d;
    float env = 0.5f*(cosf(ph) + 1.0f);
    float denv = -0.5f*POR*sinf(ph);
    sdr[n][k] = G*(-2.0f*GAMMA*dm*env + denv);
  }
  for (int idx = t; idx < cnt; idx += 256) s_j[idx] = nb_idx[a*MAXNB + idx];
  float2 a1r[8], a2r[8];
  #pragma unroll
  for (int k = 0; k < 8; k++){
    a1r[k] = *(const float2*)&dA1[a*KF + k*F + 2*lane];
    a2r[k] = *(const float2*)&dA2[a*KF + k*F + 2*lane];
  }
  __syncthreads();
  for (int n = w; n < cnt; n += 4){
    int j = s_j[n];
    float2 h1v = *(const float2*)&h1[j*F + 2*lane];
    float2 h0v = *(const float2*)&h0[j*F + 2*lane];
    float part = 0.f;
    #pragma unroll
    for (int k = 0; k < 8; k++){
      float c = a2r[k].x*h1v.x + a2r[k].y*h1v.y + a1r[k].x*h0v.x + a1r[k].y*h0v.y;
      part += sdr[n][k]*c;
    }
    #pragma unroll
    for (int o = 1; o < 64; o <<= 1) part += __shfl_xor(part, o);
    if (lane == 0) edge_s[a*MAXNB + n] = part;
  }
}

// ------- force: F_a = -sum_j (s_aj + s_ja) * (pa-pj)/d ----------------------
__global__ __launch_bounds__(64) void k_force(const float* __restrict__ pos,
        const int* __restrict__ nb_idx, const float* __restrict__ nb_d,
        const int* __restrict__ nb_cnt, const float* __restrict__ edge_s,
        float* __restrict__ out){
  int a = blockIdx.x;
  int lane = threadIdx.x;
  float pax = pos[3*a], pay = pos[3*a+1], paz = pos[3*a+2];
  int cnt = nb_cnt[a];
  float fx = 0.f, fy = 0.f, fz = 0.f;
  for (int n = lane; n < cnt; n += 64){
    int j = nb_idx[a*MAXNB + n];
    float d = nb_d[a*MAXNB + n];
    float s = edge_s[a*MAXNB + n];
    int cj = nb_cnt[j];
    int lo = 0, hi = cj - 1, p = -1;
    while (lo <= hi){
      int mid = (lo + hi) >> 1;
      int v = nb_idx[j*MAXNB + mid];
      if (v == a){ p = mid; break; }
      if (v < a) lo = mid + 1; else hi = mid - 1;
    }
    float sj = (p >= 0) ? edge_s[j*MAXNB + p] : 0.0f;
    float coef = (s + sj)/d;
    float dx = pax - pos[3*j], dy = pay - pos[3*j+1], dz = paz - pos[3*j+2];
    fx -= coef*dx; fy -= coef*dy; fz -= coef*dz;
  }
  #pragma unroll
  for (int o = 1; o < 64; o <<= 1){
    fx += __shfl_xor(fx, o); fy += __shfl_xor(fy, o); fz += __shfl_xor(fz, o);
  }
  if (lane == 0){
    out[1 + 3*a + 0] = fx;
    out[1 + 3*a + 1] = fy;
    out[1 + 3*a + 2] = fz;
  }
}

extern "C" void kernel_launch(void* const* d_in, const int* in_sizes, int n_in,
                              void* d_out, int out_size, void* d_ws, size_t ws_size,
                              hipStream_t stream){
  const float* pos   = (const float*)d_in[0];
  const int*   z     = (const int*)  d_in[1];
  const float* embed = (const float*)d_in[2];
  const float* W1    = (const float*)d_in[3];
  const float* W2    = (const float*)d_in[4];
  const float* Wr1   = (const float*)d_in[5];
  const float* Wr2   = (const float*)d_in[6];
  float* out = (float*)d_out;

  float* ws = (float*)d_ws;
  float* h0   = ws;            // NF
  float* h1   = h0 + NF;
  float* h2   = h1 + NF;
  float* m1   = h2 + NF;
  float* m2   = m1 + NF;
  float* g2b  = m2 + NF;
  float* g1b  = g2b + NF;
  float* Abuf = g1b + NF;      // NKF : A1, A2, Agg2, then dA1
  float* dA2  = Abuf + NKF;    // NKF
  float* WT1  = dA2 + NKF;     // KFF
  float* WT2  = WT1 + KFF;     // KFF
  float* WD2  = WT2 + KFF;     // KFF
  float* Wr1T = WD2 + KFF;     // FF
  float* e_at = Wr1T + FF;     // N
  float* nb_d = e_at + N_ATOMS;        // N*MAXNB
  float* edge_s = nb_d + N_ATOMS*MAXNB;// N*MAXNB
  int* nb_idx = (int*)(edge_s + N_ATOMS*MAXNB); // N*MAXNB
  int* nb_cnt = nb_idx + N_ATOMS*MAXNB;         // N

  k_nb<<<N_ATOMS, 64, 0, stream>>>(pos, nb_idx, nb_d, nb_cnt);
  k_embed<<<NF/256, 256, 0, stream>>>(z, embed, h0);
  k_wprep<<<KFF/256, 256, 0, stream>>>(W1, W2, Wr1, WT1, WT2, WD2, Wr1T);

  // forward
  k_agg<<<N_ATOMS, 256, 0, stream>>>(h0, nb_idx, nb_d, nb_cnt, Abuf);
  k_gemm_fwd<<<N_ATOMS/16, 256, 0, stream>>>(Abuf, W1, h0, m1, m1, h1, 0);
  k_agg<<<N_ATOMS, 256, 0, stream>>>(h1, nb_idx, nb_d, nb_cnt, Abuf);
  k_gemm_fwd<<<N_ATOMS/16, 256, 0, stream>>>(Abuf, W2, h1, m2, m2, h2, 0);

  // readout + energy
  k_readout<<<N_ATOMS/8, 128, 0, stream>>>(h2, m2, Wr1, Wr1T, Wr2, e_at, g2b);
  k_esum<<<1, 256, 0, stream>>>(e_at, out);

  // backward
  k_gemm_bwd<<<dim3(N_ATOMS/16, 4), 256, 0, stream>>>(g2b, WT2, dA2);
  k_agg<<<N_ATOMS, 256, 0, stream>>>(g2b, nb_idx, nb_d, nb_cnt, Abuf);      // Agg2
  k_gemm_fwd<<<N_ATOMS/16, 256, 0, stream>>>(Abuf, WD2, g2b, m1, g1b, g1b, 1); // g1
  k_gemm_bwd<<<dim3(N_ATOMS/16, 4), 256, 0, stream>>>(g1b, WT1, Abuf);      // dA1
  k_edge<<<N_ATOMS, 256, 0, stream>>>(Abuf, dA2, h0, h1, nb_idx, nb_d, nb_cnt, edge_s);
  k_force<<<N_ATOMS, 64, 0, stream>>>(pos, nb_idx, nb_d, nb_cnt, edge_s, out);
}

// Round 4
// 341.375 us; speedup vs baseline: 1.3499x; 1.1095x over previous
//
#include <hip/hip_runtime.h>
#include <math.h>

#define N_ATOMS 4096
#define F 128
#define K 8
#define KF 1024           // K*F
#define KFF 131072        // K*F*F
#define FF 16384          // F*F
#define NF 524288         // N*F
#define NF4 131072        // NF/4
#define NKF 4194304       // N*K*F
#define MAXNB 128
#define RMAX 5.0f
#define GAMMA 2.56f       // (K/RMAX)^2
#define MU_STEP 0.714285714285714f  // RMAX/(K-1)
#define PI_F 3.14159265358979323846f
#define POR (PI_F / RMAX)

__device__ __forceinline__ float sigm(float x){ return 1.0f/(1.0f + expf(-x)); }
#define FMA4(acc, s, vv) { (acc).x += (s)*(vv).x; (acc).y += (s)*(vv).y; (acc).z += (s)*(vv).z; (acc).w += (s)*(vv).w; }

// ---------------- neighbor list (deterministic ballot compaction) -----------
__global__ __launch_bounds__(64) void k_nb(const float* __restrict__ pos,
        int* __restrict__ nb_idx, float* __restrict__ nb_d, int* __restrict__ nb_cnt){
  int i = blockIdx.x;
  int lane = threadIdx.x;
  float pix = pos[3*i], piy = pos[3*i+1], piz = pos[3*i+2];
  float sqi = pix*pix + piy*piy + piz*piz;
  int count = 0;
  for (int jb = 0; jb < N_ATOMS; jb += 64){
    int j = jb + lane;
    float pjx = pos[3*j], pjy = pos[3*j+1], pjz = pos[3*j+2];
    float sqj = pjx*pjx + pjy*pjy + pjz*pjz;
    float dot = pix*pjx + piy*pjy + piz*pjz;
    float d2 = sqi + sqj - 2.0f*dot;
    float d = sqrtf(d2);
    bool pred = (j != i) && (d2 > 0.0f) && (d < RMAX);
    unsigned long long m = __ballot(pred);
    int off = __popcll(m & ((1ull << lane) - 1ull));
    if (pred){
      int p = count + off;
      if (p < MAXNB){ nb_idx[i*MAXNB + p] = j; nb_d[i*MAXNB + p] = d; }
    }
    count += __popcll(m);
  }
  if (lane == 0) nb_cnt[i] = count > MAXNB ? MAXNB : count;
}

// ---------------- h0 = embed[z] ---------------------------------------------
__global__ __launch_bounds__(256) void k_embed(const int* __restrict__ z,
        const float* __restrict__ embed, float* __restrict__ h0){
  int idx = blockIdx.x*256 + threadIdx.x;
  int i = idx >> 7, f = idx & 127;
  h0[idx] = embed[z[i]*F + f];
}

// ---------------- weight transposes -----------------------------------------
__global__ __launch_bounds__(256) void k_wprep(const float* __restrict__ W1,
        const float* __restrict__ W2, const float* __restrict__ Wr1,
        float* __restrict__ WT1, float* __restrict__ WT2,
        float* __restrict__ WD2, float* __restrict__ Wr1T){
  int idx = blockIdx.x*256 + threadIdx.x;
  {
    int g = idx >> 10, kf = idx & 1023;
    int k = kf >> 7, f = kf & 127;
    WT1[idx] = W1[k*FF + f*F + g];
    WT2[idx] = W2[k*FF + f*F + g];
  }
  {
    int k = idx >> 14, g = (idx >> 7) & 127, f = idx & 127;
    WD2[idx] = W2[k*FF + f*F + g];
  }
  if (idx < FF){
    int f = idx >> 7, g = idx & 127;
    Wr1T[idx] = Wr1[g*F + f];
  }
}

// ---------------- A[a,k,f] = sum_n rbf_k(d_an) * h[j_n,f] -------------------
__global__ __launch_bounds__(256) void k_agg(const float* __restrict__ h_in,
        const int* __restrict__ nb_idx, const float* __restrict__ nb_d,
        const int* __restrict__ nb_cnt, float* __restrict__ A){
  int a = blockIdx.x;
  int t = threadIdx.x;
  int f = t & 127;
  int kq = (t >> 7) * 4;
  __shared__ float s_rbf[MAXNB][8];
  __shared__ int s_j[MAXNB];
  int cnt = nb_cnt[a];
  for (int idx = t; idx < cnt*8; idx += 256){
    int n = idx >> 3, k = idx & 7;
    float d = nb_d[a*MAXNB + n];
    float dm = d - MU_STEP*(float)k;
    float env = 0.5f*(cosf(POR*d) + 1.0f);
    s_rbf[n][k] = expf(-GAMMA*dm*dm)*env;
  }
  for (int idx = t; idx < cnt; idx += 256) s_j[idx] = nb_idx[a*MAXNB + idx];
  __syncthreads();
  float a0=0.f, a1=0.f, a2=0.f, a3=0.f;
  int n = 0;
  for (; n + 2 <= cnt; n += 2){
    float hv0 = h_in[s_j[n]*F + f];
    float hv1 = h_in[s_j[n+1]*F + f];
    float4 r0 = *(const float4*)&s_rbf[n][kq];
    float4 r1 = *(const float4*)&s_rbf[n+1][kq];
    a0 += r0.x*hv0 + r1.x*hv1;
    a1 += r0.y*hv0 + r1.y*hv1;
    a2 += r0.z*hv0 + r1.z*hv1;
    a3 += r0.w*hv0 + r1.w*hv1;
  }
  if (n < cnt){
    float hv0 = h_in[s_j[n]*F + f];
    float4 r0 = *(const float4*)&s_rbf[n][kq];
    a0 += r0.x*hv0; a1 += r0.y*hv0; a2 += r0.z*hv0; a3 += r0.w*hv0;
  }
  A[a*KF + (kq+0)*F + f] = a0;
  A[a*KF + (kq+1)*F + f] = a1;
  A[a*KF + (kq+2)*F + f] = a2;
  A[a*KF + (kq+3)*F + f] = a3;
}

// ------- split-K GEMM: part[sl][i][g] = sum_{kf in slice} A[i,kf] W[kf,g] ---
// grid (256, 4), block 256.  16 rows/block, K-slice 256, chunks of 32.
__global__ __launch_bounds__(256) void k_gemm_split(const float* __restrict__ A,
        const float* __restrict__ W, float* __restrict__ part){
  __shared__ float sA[2][16*32];    // 2 KB each
  __shared__ float sW[2][32*128];   // 16 KB each
  int t = threadIdx.x;
  int rb = blockIdx.x * 16;
  int sl = blockIdx.y;
  int k0 = sl * 256;
  int c4 = t & 31, r0 = (t >> 5) * 2;
  bool la = t < 128;
  const float4* Aq = (const float4*)(A + (rb + (t>>3))*KF + k0) + (t & 7);
  const float4* Wq = (const float4*)W + k0*32;
  float4 ra = {0,0,0,0};
  float4 rw[4];
  if (la) ra = Aq[0];
  #pragma unroll
  for (int s = 0; s < 4; s++) rw[s] = Wq[t + s*256];
  if (la) ((float4*)sA[0])[t] = ra;
  #pragma unroll
  for (int s = 0; s < 4; s++) ((float4*)sW[0])[t + s*256] = rw[s];
  __syncthreads();
  float4 acc0 = {0,0,0,0}, acc1 = {0,0,0,0};
  int cur = 0;
  for (int ch = 0; ch < 8; ch++){
    if (ch < 7){
      if (la) ra = Aq[(ch+1)*8];
      #pragma unroll
      for (int s = 0; s < 4; s++) rw[s] = Wq[(ch+1)*1024 + t + s*256];
    }
    const float4* cA = (const float4*)sA[cur];
    const float4* cW = (const float4*)sW[cur];
    #pragma unroll
    for (int kq = 0; kq < 8; kq++){
      float4 a0 = cA[r0*8 + kq];
      float4 a1 = cA[(r0+1)*8 + kq];
      float4 w0 = cW[(kq*4+0)*32 + c4];
      float4 w1 = cW[(kq*4+1)*32 + c4];
      float4 w2 = cW[(kq*4+2)*32 + c4];
      float4 w3 = cW[(kq*4+3)*32 + c4];
      FMA4(acc0, a0.x, w0) FMA4(acc0, a0.y, w1) FMA4(acc0, a0.z, w2) FMA4(acc0, a0.w, w3)
      FMA4(acc1, a1.x, w0) FMA4(acc1, a1.y, w1) FMA4(acc1, a1.z, w2) FMA4(acc1, a1.w, w3)
    }
    if (ch < 7){
      if (la) ((float4*)sA[cur^1])[t] = ra;
      #pragma unroll
      for (int s = 0; s < 4; s++) ((float4*)sW[cur^1])[t + s*256] = rw[s];
    }
    __syncthreads();
    cur ^= 1;
  }
  float4* pp = (float4*)(part + sl*NF);
  pp[(rb+r0)*32 + c4]   = acc0;
  pp[(rb+r0+1)*32 + c4] = acc1;
}

// ------- reduce 4 split-K partials + epilogue -------------------------------
// mode 0: m = sum + addv; out_m = m; out_h = silu(m)
// mode 1: out_h = (sum + addv) * silu'(msrc)
__global__ __launch_bounds__(256) void k_reduce(const float* __restrict__ part,
        const float* __restrict__ addv, const float* __restrict__ msrc,
        float* __restrict__ out_m, float* __restrict__ out_h, int mode){
  int idx = blockIdx.x*256 + threadIdx.x;   // over NF4 float4s
  const float4* p = (const float4*)part;
  float4 s = p[idx];
  float4 b = p[idx + NF4];
  float4 c = p[idx + 2*NF4];
  float4 dd = p[idx + 3*NF4];
  s.x += b.x + c.x + dd.x; s.y += b.y + c.y + dd.y;
  s.z += b.z + c.z + dd.z; s.w += b.w + c.w + dd.w;
  float4 av = ((const float4*)addv)[idx];
  s.x += av.x; s.y += av.y; s.z += av.z; s.w += av.w;
  if (mode == 0){
    ((float4*)out_m)[idx] = s;
    float4 o;
    o.x = s.x*sigm(s.x); o.y = s.y*sigm(s.y); o.z = s.z*sigm(s.z); o.w = s.w*sigm(s.w);
    ((float4*)out_h)[idx] = o;
  } else {
    float4 mm = ((const float4*)msrc)[idx];
    float4 o; float sg;
    sg = sigm(mm.x); o.x = s.x*(sg*(1.f+mm.x*(1.f-sg)));
    sg = sigm(mm.y); o.y = s.y*(sg*(1.f+mm.y*(1.f-sg)));
    sg = sigm(mm.z); o.z = s.z*(sg*(1.f+mm.z*(1.f-sg)));
    sg = sigm(mm.w); o.w = s.w*(sg*(1.f+mm.w*(1.f-sg)));
    ((float4*)out_h)[idx] = o;
  }
}

// ------- GEMM bwd: dA[i,kf] = sum_g G[i,g] WT[g,kf] -------------------------
// tile 16 rows x 256 cols (grid.y = 4 col slices), 256 thr, reg-prefetch W.
__global__ __launch_bounds__(256) void k_gemm_bwd(const float* __restrict__ G,
        const float* __restrict__ WT, float* __restrict__ dA){
  __shared__ float sg[16*128];    // 8 KB
  __shared__ float sW[32*256];    // 32 KB
  int t = threadIdx.x;
  int rb = blockIdx.x * 16;
  int nb0 = blockIdx.y * 256;
  int nq = nb0 >> 2;
  int c4 = t & 31, r0 = (t >> 5)*2;
  const float4* G4 = (const float4*)(G + rb*128);
  float4 rg0 = G4[t], rg1 = G4[t+256];
  const float4* WT4 = (const float4*)WT;
  float4 rwv[8];
  #pragma unroll
  for (int s = 0; s < 8; s++){
    int idx = t + s*256;
    rwv[s] = WT4[((idx>>6))*256 + nq + (idx & 63)];
  }
  ((float4*)sg)[t] = rg0; ((float4*)sg)[t+256] = rg1;
  float4 accA0 = {0,0,0,0}, accB0 = {0,0,0,0};
  float4 accA1 = {0,0,0,0}, accB1 = {0,0,0,0};
  for (int kc = 0; kc < 4; kc++){
    #pragma unroll
    for (int s = 0; s < 8; s++) ((float4*)sW)[t + s*256] = rwv[s];
    __syncthreads();
    if (kc < 3){
      #pragma unroll
      for (int s = 0; s < 8; s++){
        int idx = t + s*256;
        rwv[s] = WT4[((kc+1)*32 + (idx>>6))*256 + nq + (idx & 63)];
      }
    }
    #pragma unroll 8
    for (int k = 0; k < 32; k++){
      float a0 = sg[r0*128 + kc*32 + k];
      float a1 = sg[(r0+1)*128 + kc*32 + k];
      float4 w0 = *(const float4*)&sW[k*256 + c4*4];
      float4 w1 = *(const float4*)&sW[k*256 + 128 + c4*4];
      FMA4(accA0, a0, w0) FMA4(accB0, a0, w1)
      FMA4(accA1, a1, w0) FMA4(accB1, a1, w1)
    }
    __syncthreads();
  }
  *(float4*)&dA[(rb+r0)*1024 + nb0 + c4*4]         = accA0;
  *(float4*)&dA[(rb+r0)*1024 + nb0 + 128 + c4*4]   = accB0;
  *(float4*)&dA[(rb+r0+1)*1024 + nb0 + c4*4]       = accA1;
  *(float4*)&dA[(rb+r0+1)*1024 + nb0 + 128 + c4*4] = accB1;
}

// ---------------- readout fwd + bwd: e_atom, g2 = dE/dm2 --------------------
__global__ __launch_bounds__(128) void k_readout(const float* __restrict__ h2,
        const float* __restrict__ m2, const float* __restrict__ Wr1,
        const float* __restrict__ Wr1T, const float* __restrict__ Wr2,
        float* __restrict__ e_at, float* __restrict__ g2){
  int b = blockIdx.x * 8;
  int t = threadIdx.x;
  int lane = t & 63, wv = t >> 6;
  __shared__ float sh[128][8];
  __shared__ float sdu[128][8];
  __shared__ float red[2][8];
  #pragma unroll
  for (int r = 0; r < 8; r++) sh[t][r] = h2[(b+r)*F + t];
  __syncthreads();
  float u[8] = {0,0,0,0,0,0,0,0};
  for (int g = 0; g < 128; g++){
    float wvv = Wr1[g*F + t];
    float4 s0 = *(const float4*)&sh[g][0];
    float4 s1 = *(const float4*)&sh[g][4];
    u[0] += s0.x*wvv; u[1] += s0.y*wvv; u[2] += s0.z*wvv; u[3] += s0.w*wvv;
    u[4] += s1.x*wvv; u[5] += s1.y*wvv; u[6] += s1.z*wvv; u[7] += s1.w*wvv;
  }
  float w2 = Wr2[t];
  #pragma unroll
  for (int r = 0; r < 8; r++){
    float sg = sigm(u[r]);
    float e = u[r]*sg*w2;
    #pragma unroll
    for (int o = 1; o < 64; o <<= 1) e += __shfl_xor(e, o);
    if (lane == 0) red[wv][r] = e;
    sdu[t][r] = w2*(sg*(1.f + u[r]*(1.f - sg)));
  }
  __syncthreads();
  if (t < 8) e_at[b+t] = red[0][t] + red[1][t];
  float dh[8] = {0,0,0,0,0,0,0,0};
  for (int f = 0; f < 128; f++){
    float wvv = Wr1T[f*F + t];
    float4 s0 = *(const float4*)&sdu[f][0];
    float4 s1 = *(const float4*)&sdu[f][4];
    dh[0] += s0.x*wvv; dh[1] += s0.y*wvv; dh[2] += s0.z*wvv; dh[3] += s0.w*wvv;
    dh[4] += s1.x*wvv; dh[5] += s1.y*wvv; dh[6] += s1.z*wvv; dh[7] += s1.w*wvv;
  }
  #pragma unroll
  for (int r = 0; r < 8; r++){
    float mm = m2[(b+r)*F + t];
    float sg = sigm(mm);
    g2[(b+r)*F + t] = dh[r]*(sg*(1.f + mm*(1.f - sg)));
  }
}

// ---------------- deterministic energy sum ----------------------------------
__global__ __launch_bounds__(256) void k_esum(const float* __restrict__ e_at,
        float* __restrict__ out){
  __shared__ float red[256];
  float s = 0.f;
  for (int i = threadIdx.x; i < N_ATOMS; i += 256) s += e_at[i];
  red[threadIdx.x] = s;
  __syncthreads();
  for (int o = 128; o > 0; o >>= 1){
    if (threadIdx.x < o) red[threadIdx.x] += red[threadIdx.x + o];
    __syncthreads();
  }
  if (threadIdx.x == 0) out[0] = red[0];
}

// ------- per-edge scalar, one dA/h pair per pass ----------------------------
// edge_s[a,n] (+)= sum_k dr_k(d_an) * sum_f dA[a,k,f] * h[j_n, f]
__global__ __launch_bounds__(256) void k_edge(const float* __restrict__ dA,
        const float* __restrict__ h,
        const int* __restrict__ nb_idx, const float* __restrict__ nb_d,
        const int* __restrict__ nb_cnt, float* __restrict__ edge_s, int accum){
  int a = blockIdx.x;
  int t = threadIdx.x;
  int lane = t & 63, w = t >> 6;
  __shared__ float sdr[MAXNB][8];
  __shared__ int s_j[MAXNB];
  int cnt = nb_cnt[a];
  for (int idx = t; idx < cnt*8; idx += 256){
    int n = idx >> 3, k = idx & 7;
    float d = nb_d[a*MAXNB + n];
    float dm = d - MU_STEP*(float)k;
    float G = expf(-GAMMA*dm*dm);
    float ph = POR*d;
    float env = 0.5f*(cosf(ph) + 1.0f);
    float denv = -0.5f*POR*sinf(ph);
    sdr[n][k] = G*(-2.0f*GAMMA*dm*env + denv);
  }
  for (int idx = t; idx < cnt; idx += 256) s_j[idx] = nb_idx[a*MAXNB + idx];
  float2 ar[8];
  #pragma unroll
  for (int k = 0; k < 8; k++)
    ar[k] = *(const float2*)&dA[a*KF + k*F + 2*lane];
  __syncthreads();
  for (int n = w; n < cnt; n += 4){
    int j = s_j[n];
    float2 hv = *(const float2*)&h[j*F + 2*lane];
    float part = 0.f;
    #pragma unroll
    for (int k = 0; k < 8; k++)
      part += sdr[n][k]*(ar[k].x*hv.x + ar[k].y*hv.y);
    #pragma unroll
    for (int o = 1; o < 64; o <<= 1) part += __shfl_xor(part, o);
    if (lane == 0){
      if (accum) edge_s[a*MAXNB + n] += part;
      else       edge_s[a*MAXNB + n]  = part;
    }
  }
}

// ------- force: F_a = -sum_j (s_aj + s_ja) * (pa-pj)/d ----------------------
__global__ __launch_bounds__(64) void k_force(const float* __restrict__ pos,
        const int* __restrict__ nb_idx, const float* __restrict__ nb_d,
        const int* __restrict__ nb_cnt, const float* __restrict__ edge_s,
        float* __restrict__ out){
  int a = blockIdx.x;
  int lane = threadIdx.x;
  float pax = pos[3*a], pay = pos[3*a+1], paz = pos[3*a+2];
  int cnt = nb_cnt[a];
  float fx = 0.f, fy = 0.f, fz = 0.f;
  for (int n = lane; n < cnt; n += 64){
    int j = nb_idx[a*MAXNB + n];
    float d = nb_d[a*MAXNB + n];
    float s = edge_s[a*MAXNB + n];
    int cj = nb_cnt[j];
    int lo = 0, hi = cj - 1, p = -1;
    while (lo <= hi){
      int mid = (lo + hi) >> 1;
      int v = nb_idx[j*MAXNB + mid];
      if (v == a){ p = mid; break; }
      if (v < a) lo = mid + 1; else hi = mid - 1;
    }
    float sj = (p >= 0) ? edge_s[j*MAXNB + p] : 0.0f;
    float coef = (s + sj)/d;
    float dx = pax - pos[3*j], dy = pay - pos[3*j+1], dz = paz - pos[3*j+2];
    fx -= coef*dx; fy -= coef*dy; fz -= coef*dz;
  }
  #pragma unroll
  for (int o = 1; o < 64; o <<= 1){
    fx += __shfl_xor(fx, o); fy += __shfl_xor(fy, o); fz += __shfl_xor(fz, o);
  }
  if (lane == 0){
    out[1 + 3*a + 0] = fx;
    out[1 + 3*a + 1] = fy;
    out[1 + 3*a + 2] = fz;
  }
}

extern "C" void kernel_launch(void* const* d_in, const int* in_sizes, int n_in,
                              void* d_out, int out_size, void* d_ws, size_t ws_size,
                              hipStream_t stream){
  const float* pos   = (const float*)d_in[0];
  const int*   z     = (const int*)  d_in[1];
  const float* embed = (const float*)d_in[2];
  const float* W1    = (const float*)d_in[3];
  const float* W2    = (const float*)d_in[4];
  const float* Wr1   = (const float*)d_in[5];
  const float* Wr2   = (const float*)d_in[6];
  float* out = (float*)d_out;

  float* ws = (float*)d_ws;
  float* h0   = ws;            // NF
  float* h1   = h0 + NF;
  float* h2   = h1 + NF;
  float* m1   = h2 + NF;
  float* m2   = m1 + NF;
  float* g2b  = m2 + NF;
  float* g1b  = g2b + NF;
  float* Abuf = g1b + NF;      // NKF : A1, A2, Agg2
  float* Bbuf = Abuf + NKF;    // NKF : split partials / dA2 / dA1
  float* WT1  = Bbuf + NKF;    // KFF
  float* WT2  = WT1 + KFF;     // KFF
  float* WD2  = WT2 + KFF;     // KFF
  float* Wr1T = WD2 + KFF;     // FF
  float* e_at = Wr1T + FF;     // N
  float* nb_d = e_at + N_ATOMS;        // N*MAXNB
  float* edge_s = nb_d + N_ATOMS*MAXNB;// N*MAXNB
  int* nb_idx = (int*)(edge_s + N_ATOMS*MAXNB); // N*MAXNB
  int* nb_cnt = nb_idx + N_ATOMS*MAXNB;         // N

  k_nb<<<N_ATOMS, 64, 0, stream>>>(pos, nb_idx, nb_d, nb_cnt);
  k_embed<<<NF/256, 256, 0, stream>>>(z, embed, h0);
  k_wprep<<<KFF/256, 256, 0, stream>>>(W1, W2, Wr1, WT1, WT2, WD2, Wr1T);

  // forward layer 1
  k_agg<<<N_ATOMS, 256, 0, stream>>>(h0, nb_idx, nb_d, nb_cnt, Abuf);
  k_gemm_split<<<dim3(N_ATOMS/16, 4), 256, 0, stream>>>(Abuf, W1, Bbuf);
  k_reduce<<<NF4/256, 256, 0, stream>>>(Bbuf, h0, h0, m1, h1, 0);
  // forward layer 2
  k_agg<<<N_ATOMS, 256, 0, stream>>>(h1, nb_idx, nb_d, nb_cnt, Abuf);
  k_gemm_split<<<dim3(N_ATOMS/16, 4), 256, 0, stream>>>(Abuf, W2, Bbuf);
  k_reduce<<<NF4/256, 256, 0, stream>>>(Bbuf, h1, h1, m2, h2, 0);

  // readout + energy
  k_readout<<<N_ATOMS/8, 128, 0, stream>>>(h2, m2, Wr1, Wr1T, Wr2, e_at, g2b);
  k_esum<<<1, 256, 0, stream>>>(e_at, out);

  // backward
  k_gemm_bwd<<<dim3(N_ATOMS/16, 4), 256, 0, stream>>>(g2b, WT2, Bbuf);          // dA2
  k_edge<<<N_ATOMS, 256, 0, stream>>>(Bbuf, h1, nb_idx, nb_d, nb_cnt, edge_s, 0);
  k_agg<<<N_ATOMS, 256, 0, stream>>>(g2b, nb_idx, nb_d, nb_cnt, Abuf);          // Agg2
  k_gemm_split<<<dim3(N_ATOMS/16, 4), 256, 0, stream>>>(Abuf, WD2, Bbuf);
  k_reduce<<<NF4/256, 256, 0, stream>>>(Bbuf, g2b, m1, g1b, g1b, 1);            // g1
  k_gemm_bwd<<<dim3(N_ATOMS/16, 4), 256, 0, stream>>>(g1b, WT1, Bbuf);          // dA1
  k_edge<<<N_ATOMS, 256, 0, stream>>>(Bbuf, h0, nb_idx, nb_d, nb_cnt, edge_s, 1);
  k_force<<<N_ATOMS, 64, 0, stream>>>(pos, nb_idx, nb_d, nb_cnt, edge_s, out);
}

// Round 5
// 311.894 us; speedup vs baseline: 1.4775x; 1.0945x over previous
//
#include <hip/hip_runtime.h>
#include <math.h>

#define N_ATOMS 4096
#define F 128
#define K 8
#define KF 1024           // K*F
#define KFF 131072        // K*F*F
#define FF 16384          // F*F
#define NF 524288         // N*F
#define NF4 131072        // NF/4
#define NKF 4194304       // N*K*F
#define MAXNB 128
#define RMAX 5.0f
#define GAMMA 2.56f       // (K/RMAX)^2
#define MU_STEP 0.714285714285714f  // RMAX/(K-1)
#define PI_F 3.14159265358979323846f
#define POR (PI_F / RMAX)

__device__ __forceinline__ float sigm(float x){ return 1.0f/(1.0f + expf(-x)); }
#define FMA4(acc, s, vv) { (acc).x += (s)*(vv).x; (acc).y += (s)*(vv).y; (acc).z += (s)*(vv).z; (acc).w += (s)*(vv).w; }

// ---------------- neighbor list (deterministic ballot compaction) -----------
__global__ __launch_bounds__(64) void k_nb(const float* __restrict__ pos,
        int* __restrict__ nb_idx, float* __restrict__ nb_d, int* __restrict__ nb_cnt){
  int i = blockIdx.x;
  int lane = threadIdx.x;
  float pix = pos[3*i], piy = pos[3*i+1], piz = pos[3*i+2];
  float sqi = pix*pix + piy*piy + piz*piz;
  int count = 0;
  for (int jb = 0; jb < N_ATOMS; jb += 64){
    int j = jb + lane;
    float pjx = pos[3*j], pjy = pos[3*j+1], pjz = pos[3*j+2];
    float sqj = pjx*pjx + pjy*pjy + pjz*pjz;
    float dot = pix*pjx + piy*pjy + piz*pjz;
    float d2 = sqi + sqj - 2.0f*dot;
    float d = sqrtf(d2);
    bool pred = (j != i) && (d2 > 0.0f) && (d < RMAX);
    unsigned long long m = __ballot(pred);
    int off = __popcll(m & ((1ull << lane) - 1ull));
    if (pred){
      int p = count + off;
      if (p < MAXNB){ nb_idx[i*MAXNB + p] = j; nb_d[i*MAXNB + p] = d; }
    }
    count += __popcll(m);
  }
  if (lane == 0) nb_cnt[i] = count > MAXNB ? MAXNB : count;
}

// ---------------- h0 = embed[z] ---------------------------------------------
__global__ __launch_bounds__(256) void k_embed(const int* __restrict__ z,
        const float* __restrict__ embed, float* __restrict__ h0){
  int idx = blockIdx.x*256 + threadIdx.x;
  int i = idx >> 7, f = idx & 127;
  h0[idx] = embed[z[i]*F + f];
}

// ---------------- weight transposes -----------------------------------------
__global__ __launch_bounds__(256) void k_wprep(const float* __restrict__ W1,
        const float* __restrict__ W2, const float* __restrict__ Wr1,
        float* __restrict__ WT1, float* __restrict__ WT2,
        float* __restrict__ WD2, float* __restrict__ Wr1T){
  int idx = blockIdx.x*256 + threadIdx.x;
  {
    int g = idx >> 10, kf = idx & 1023;
    int k = kf >> 7, f = kf & 127;
    WT1[idx] = W1[k*FF + f*F + g];
    WT2[idx] = W2[k*FF + f*F + g];
  }
  {
    int k = idx >> 14, g = (idx >> 7) & 127, f = idx & 127;
    WD2[idx] = W2[k*FF + f*F + g];
  }
  if (idx < FF){
    int f = idx >> 7, g = idx & 127;
    Wr1T[idx] = Wr1[g*F + f];
  }
}

// ---------------- A[a,k,f] = sum_n rbf_k(d_an) * h[j_n,f] -------------------
__global__ __launch_bounds__(256) void k_agg(const float* __restrict__ h_in,
        const int* __restrict__ nb_idx, const float* __restrict__ nb_d,
        const int* __restrict__ nb_cnt, float* __restrict__ A){
  int a = blockIdx.x;
  int t = threadIdx.x;
  int f = t & 127;
  int kq = (t >> 7) * 4;
  __shared__ float s_rbf[MAXNB][8];
  __shared__ int s_j[MAXNB];
  int cnt = nb_cnt[a];
  for (int idx = t; idx < cnt*8; idx += 256){
    int n = idx >> 3, k = idx & 7;
    float d = nb_d[a*MAXNB + n];
    float dm = d - MU_STEP*(float)k;
    float env = 0.5f*(cosf(POR*d) + 1.0f);
    s_rbf[n][k] = expf(-GAMMA*dm*dm)*env;
  }
  for (int idx = t; idx < cnt; idx += 256) s_j[idx] = nb_idx[a*MAXNB + idx];
  __syncthreads();
  float a0=0.f, a1=0.f, a2=0.f, a3=0.f;
  int n = 0;
  for (; n + 2 <= cnt; n += 2){
    float hv0 = h_in[s_j[n]*F + f];
    float hv1 = h_in[s_j[n+1]*F + f];
    float4 r0 = *(const float4*)&s_rbf[n][kq];
    float4 r1 = *(const float4*)&s_rbf[n+1][kq];
    a0 += r0.x*hv0 + r1.x*hv1;
    a1 += r0.y*hv0 + r1.y*hv1;
    a2 += r0.z*hv0 + r1.z*hv1;
    a3 += r0.w*hv0 + r1.w*hv1;
  }
  if (n < cnt){
    float hv0 = h_in[s_j[n]*F + f];
    float4 r0 = *(const float4*)&s_rbf[n][kq];
    a0 += r0.x*hv0; a1 += r0.y*hv0; a2 += r0.z*hv0; a3 += r0.w*hv0;
  }
  A[a*KF + (kq+0)*F + f] = a0;
  A[a*KF + (kq+1)*F + f] = a1;
  A[a*KF + (kq+2)*F + f] = a2;
  A[a*KF + (kq+3)*F + f] = a3;
}

// ------- split-K GEMM: part[sl][i][g] = sum_{kf in slice} A[i,kf] W[kf,g] ---
__global__ __launch_bounds__(256) void k_gemm_split(const float* __restrict__ A,
        const float* __restrict__ W, float* __restrict__ part){
  __shared__ float sA[2][16*32];
  __shared__ float sW[2][32*128];
  int t = threadIdx.x;
  int rb = blockIdx.x * 16;
  int sl = blockIdx.y;
  int k0 = sl * 256;
  int c4 = t & 31, r0 = (t >> 5) * 2;
  bool la = t < 128;
  const float4* Aq = (const float4*)(A + (rb + (t>>3))*KF + k0) + (t & 7);
  const float4* Wq = (const float4*)W + k0*32;
  float4 ra = {0,0,0,0};
  float4 rw[4];
  if (la) ra = Aq[0];
  #pragma unroll
  for (int s = 0; s < 4; s++) rw[s] = Wq[t + s*256];
  if (la) ((float4*)sA[0])[t] = ra;
  #pragma unroll
  for (int s = 0; s < 4; s++) ((float4*)sW[0])[t + s*256] = rw[s];
  __syncthreads();
  float4 acc0 = {0,0,0,0}, acc1 = {0,0,0,0};
  int cur = 0;
  for (int ch = 0; ch < 8; ch++){
    if (ch < 7){
      if (la) ra = Aq[(ch+1)*8];
      #pragma unroll
      for (int s = 0; s < 4; s++) rw[s] = Wq[(ch+1)*1024 + t + s*256];
    }
    const float4* cA = (const float4*)sA[cur];
    const float4* cW = (const float4*)sW[cur];
    #pragma unroll
    for (int kq = 0; kq < 8; kq++){
      float4 a0 = cA[r0*8 + kq];
      float4 a1 = cA[(r0+1)*8 + kq];
      float4 w0 = cW[(kq*4+0)*32 + c4];
      float4 w1 = cW[(kq*4+1)*32 + c4];
      float4 w2 = cW[(kq*4+2)*32 + c4];
      float4 w3 = cW[(kq*4+3)*32 + c4];
      FMA4(acc0, a0.x, w0) FMA4(acc0, a0.y, w1) FMA4(acc0, a0.z, w2) FMA4(acc0, a0.w, w3)
      FMA4(acc1, a1.x, w0) FMA4(acc1, a1.y, w1) FMA4(acc1, a1.z, w2) FMA4(acc1, a1.w, w3)
    }
    if (ch < 7){
      if (la) ((float4*)sA[cur^1])[t] = ra;
      #pragma unroll
      for (int s = 0; s < 4; s++) ((float4*)sW[cur^1])[t + s*256] = rw[s];
    }
    __syncthreads();
    cur ^= 1;
  }
  float4* pp = (float4*)(part + sl*NF);
  pp[(rb+r0)*32 + c4]   = acc0;
  pp[(rb+r0+1)*32 + c4] = acc1;
}

// ------- reduce 4 split-K partials + epilogue -------------------------------
__global__ __launch_bounds__(256) void k_reduce(const float* __restrict__ part,
        const float* __restrict__ addv, const float* __restrict__ msrc,
        float* __restrict__ out_m, float* __restrict__ out_h, int mode){
  int idx = blockIdx.x*256 + threadIdx.x;
  const float4* p = (const float4*)part;
  float4 s = p[idx];
  float4 b = p[idx + NF4];
  float4 c = p[idx + 2*NF4];
  float4 dd = p[idx + 3*NF4];
  s.x += b.x + c.x + dd.x; s.y += b.y + c.y + dd.y;
  s.z += b.z + c.z + dd.z; s.w += b.w + c.w + dd.w;
  float4 av = ((const float4*)addv)[idx];
  s.x += av.x; s.y += av.y; s.z += av.z; s.w += av.w;
  if (mode == 0){
    ((float4*)out_m)[idx] = s;
    float4 o;
    o.x = s.x*sigm(s.x); o.y = s.y*sigm(s.y); o.z = s.z*sigm(s.z); o.w = s.w*sigm(s.w);
    ((float4*)out_h)[idx] = o;
  } else {
    float4 mm = ((const float4*)msrc)[idx];
    float4 o; float sg;
    sg = sigm(mm.x); o.x = s.x*(sg*(1.f+mm.x*(1.f-sg)));
    sg = sigm(mm.y); o.y = s.y*(sg*(1.f+mm.y*(1.f-sg)));
    sg = sigm(mm.z); o.z = s.z*(sg*(1.f+mm.z*(1.f-sg)));
    sg = sigm(mm.w); o.w = s.w*(sg*(1.f+mm.w*(1.f-sg)));
    ((float4*)out_h)[idx] = o;
  }
}

// ------- GEMM bwd: dA[4096,1024] = G[4096,128] @ WT[128,1024] ---------------
// 64x128 tile, grid (64,8), 256 thr, K-chunks of 32, double-buffered LDS,
// thread tile 4 rows x (c4, c4+64) cols.
__global__ __launch_bounds__(256) void k_gemm_bwd(const float* __restrict__ G,
        const float* __restrict__ WT, float* __restrict__ dA){
  __shared__ float sG[2][64*33];    // padded stride 33: conflict-free b32
  __shared__ float sW[2][32*128];
  int t = threadIdx.x;
  int rb = blockIdx.x * 64;
  int nb0 = blockIdx.y * 128;
  int nq4 = blockIdx.y * 32;
  int c4 = (t & 15) * 4;
  int rg = (t >> 4) * 4;
  const float4* G4 = (const float4*)G;
  const float4* WT4 = (const float4*)WT;
  float4 ra[2], rw[4];
  // load chunk 0
  #pragma unroll
  for (int s = 0; s < 2; s++){
    int q = t + s*256;
    ra[s] = G4[(rb + (q>>3))*32 + (q&7)];
  }
  #pragma unroll
  for (int s = 0; s < 4; s++){
    int q = t + s*256;
    rw[s] = WT4[(q>>5)*256 + nq4 + (q&31)];
  }
  // store chunk 0
  #pragma unroll
  for (int s = 0; s < 2; s++){
    int q = t + s*256;
    int base = (q>>3)*33 + (q&7)*4;
    sG[0][base+0] = ra[s].x; sG[0][base+1] = ra[s].y;
    sG[0][base+2] = ra[s].z; sG[0][base+3] = ra[s].w;
  }
  #pragma unroll
  for (int s = 0; s < 4; s++) ((float4*)sW[0])[t + s*256] = rw[s];
  __syncthreads();
  float4 acc[4][2];
  #pragma unroll
  for (int r = 0; r < 4; r++){ acc[r][0] = {0,0,0,0}; acc[r][1] = {0,0,0,0}; }
  int cur = 0;
  for (int kc = 0; kc < 4; kc++){
    if (kc < 3){
      #pragma unroll
      for (int s = 0; s < 2; s++){
        int q = t + s*256;
        ra[s] = G4[(rb + (q>>3))*32 + (kc+1)*8 + (q&7)];
      }
      #pragma unroll
      for (int s = 0; s < 4; s++){
        int q = t + s*256;
        rw[s] = WT4[((kc+1)*32 + (q>>5))*256 + nq4 + (q&31)];
      }
    }
    const float* cG = sG[cur];
    const float* cW = sW[cur];
    #pragma unroll
    for (int k = 0; k < 32; k++){
      float a0 = cG[(rg+0)*33 + k];
      float a1 = cG[(rg+1)*33 + k];
      float a2 = cG[(rg+2)*33 + k];
      float a3 = cG[(rg+3)*33 + k];
      float4 w0 = *(const float4*)&cW[k*128 + c4];
      float4 w1 = *(const float4*)&cW[k*128 + 64 + c4];
      FMA4(acc[0][0], a0, w0) FMA4(acc[0][1], a0, w1)
      FMA4(acc[1][0], a1, w0) FMA4(acc[1][1], a1, w1)
      FMA4(acc[2][0], a2, w0) FMA4(acc[2][1], a2, w1)
      FMA4(acc[3][0], a3, w0) FMA4(acc[3][1], a3, w1)
    }
    if (kc < 3){
      #pragma unroll
      for (int s = 0; s < 2; s++){
        int q = t + s*256;
        int base = (q>>3)*33 + (q&7)*4;
        sG[cur^1][base+0] = ra[s].x; sG[cur^1][base+1] = ra[s].y;
        sG[cur^1][base+2] = ra[s].z; sG[cur^1][base+3] = ra[s].w;
      }
      #pragma unroll
      for (int s = 0; s < 4; s++) ((float4*)sW[cur^1])[t + s*256] = rw[s];
    }
    __syncthreads();
    cur ^= 1;
  }
  #pragma unroll
  for (int r = 0; r < 4; r++){
    *(float4*)&dA[(rb+rg+r)*1024 + nb0 + c4]      = acc[r][0];
    *(float4*)&dA[(rb+rg+r)*1024 + nb0 + 64 + c4] = acc[r][1];
  }
}

// ---------------- readout fwd + bwd: e_atom, g2 = dE/dm2 --------------------
__global__ __launch_bounds__(128) void k_readout(const float* __restrict__ h2,
        const float* __restrict__ m2, const float* __restrict__ Wr1,
        const float* __restrict__ Wr1T, const float* __restrict__ Wr2,
        float* __restrict__ e_at, float* __restrict__ g2){
  int b = blockIdx.x * 8;
  int t = threadIdx.x;
  int lane = t & 63, wv = t >> 6;
  __shared__ float sh[128][8];
  __shared__ float sdu[128][8];
  __shared__ float red[2][8];
  #pragma unroll
  for (int r = 0; r < 8; r++) sh[t][r] = h2[(b+r)*F + t];
  __syncthreads();
  float u[8] = {0,0,0,0,0,0,0,0};
  for (int g = 0; g < 128; g++){
    float wvv = Wr1[g*F + t];
    float4 s0 = *(const float4*)&sh[g][0];
    float4 s1 = *(const float4*)&sh[g][4];
    u[0] += s0.x*wvv; u[1] += s0.y*wvv; u[2] += s0.z*wvv; u[3] += s0.w*wvv;
    u[4] += s1.x*wvv; u[5] += s1.y*wvv; u[6] += s1.z*wvv; u[7] += s1.w*wvv;
  }
  float w2 = Wr2[t];
  #pragma unroll
  for (int r = 0; r < 8; r++){
    float sg = sigm(u[r]);
    float e = u[r]*sg*w2;
    #pragma unroll
    for (int o = 1; o < 64; o <<= 1) e += __shfl_xor(e, o);
    if (lane == 0) red[wv][r] = e;
    sdu[t][r] = w2*(sg*(1.f + u[r]*(1.f - sg)));
  }
  __syncthreads();
  if (t < 8) e_at[b+t] = red[0][t] + red[1][t];
  float dh[8] = {0,0,0,0,0,0,0,0};
  for (int f = 0; f < 128; f++){
    float wvv = Wr1T[f*F + t];
    float4 s0 = *(const float4*)&sdu[f][0];
    float4 s1 = *(const float4*)&sdu[f][4];
    dh[0] += s0.x*wvv; dh[1] += s0.y*wvv; dh[2] += s0.z*wvv; dh[3] += s0.w*wvv;
    dh[4] += s1.x*wvv; dh[5] += s1.y*wvv; dh[6] += s1.z*wvv; dh[7] += s1.w*wvv;
  }
  #pragma unroll
  for (int r = 0; r < 8; r++){
    float mm = m2[(b+r)*F + t];
    float sg = sigm(mm);
    g2[(b+r)*F + t] = dh[r]*(sg*(1.f + mm*(1.f - sg)));
  }
}

// ---------------- deterministic energy sum ----------------------------------
__global__ __launch_bounds__(256) void k_esum(const float* __restrict__ e_at,
        float* __restrict__ out){
  __shared__ float red[256];
  float s = 0.f;
  for (int i = threadIdx.x; i < N_ATOMS; i += 256) s += e_at[i];
  red[threadIdx.x] = s;
  __syncthreads();
  for (int o = 128; o > 0; o >>= 1){
    if (threadIdx.x < o) red[threadIdx.x] += red[threadIdx.x + o];
    __syncthreads();
  }
  if (threadIdx.x == 0) out[0] = red[0];
}

// ------- per-edge scalar, one dA/h pair per pass ----------------------------
__global__ __launch_bounds__(256) void k_edge(const float* __restrict__ dA,
        const float* __restrict__ h,
        const int* __restrict__ nb_idx, const float* __restrict__ nb_d,
        const int* __restrict__ nb_cnt, float* __restrict__ edge_s, int accum){
  int a = blockIdx.x;
  int t = threadIdx.x;
  int lane = t & 63, w = t >> 6;
  __shared__ float sdr[MAXNB][8];
  __shared__ int s_j[MAXNB];
  int cnt = nb_cnt[a];
  for (int idx = t; idx < cnt*8; idx += 256){
    int n = idx >> 3, k = idx & 7;
    float d = nb_d[a*MAXNB + n];
    float dm = d - MU_STEP*(float)k;
    float G = expf(-GAMMA*dm*dm);
    float ph = POR*d;
    float env = 0.5f*(cosf(ph) + 1.0f);
    float denv = -0.5f*POR*sinf(ph);
    sdr[n][k] = G*(-2.0f*GAMMA*dm*env + denv);
  }
  for (int idx = t; idx < cnt; idx += 256) s_j[idx] = nb_idx[a*MAXNB + idx];
  float2 ar[8];
  #pragma unroll
  for (int k = 0; k < 8; k++)
    ar[k] = *(const float2*)&dA[a*KF + k*F + 2*lane];
  __syncthreads();
  for (int n = w; n < cnt; n += 4){
    int j = s_j[n];
    float2 hv = *(const float2*)&h[j*F + 2*lane];
    float part = 0.f;
    #pragma unroll
    for (int k = 0; k < 8; k++)
      part += sdr[n][k]*(ar[k].x*hv.x + ar[k].y*hv.y);
    #pragma unroll
    for (int o = 1; o < 64; o <<= 1) part += __shfl_xor(part, o);
    if (lane == 0){
      if (accum) edge_s[a*MAXNB + n] += part;
      else       edge_s[a*MAXNB + n]  = part;
    }
  }
}

// ------- force: F_a = -sum_j (s_aj + s_ja) * (pa-pj)/d ----------------------
__global__ __launch_bounds__(64) void k_force(const float* __restrict__ pos,
        const int* __restrict__ nb_idx, const float* __restrict__ nb_d,
        const int* __restrict__ nb_cnt, const float* __restrict__ edge_s,
        float* __restrict__ out){
  int a = blockIdx.x;
  int lane = threadIdx.x;
  float pax = pos[3*a], pay = pos[3*a+1], paz = pos[3*a+2];
  int cnt = nb_cnt[a];
  float fx = 0.f, fy = 0.f, fz = 0.f;
  for (int n = lane; n < cnt; n += 64){
    int j = nb_idx[a*MAXNB + n];
    float d = nb_d[a*MAXNB + n];
    float s = edge_s[a*MAXNB + n];
    int cj = nb_cnt[j];
    int lo = 0, hi = cj - 1, p = -1;
    while (lo <= hi){
      int mid = (lo + hi) >> 1;
      int v = nb_idx[j*MAXNB + mid];
      if (v == a){ p = mid; break; }
      if (v < a) lo = mid + 1; else hi = mid - 1;
    }
    float sj = (p >= 0) ? edge_s[j*MAXNB + p] : 0.0f;
    float coef = (s + sj)/d;
    float dx = pax - pos[3*j], dy = pay - pos[3*j+1], dz = paz - pos[3*j+2];
    fx -= coef*dx; fy -= coef*dy; fz -= coef*dz;
  }
  #pragma unroll
  for (int o = 1; o < 64; o <<= 1){
    fx += __shfl_xor(fx, o); fy += __shfl_xor(fy, o); fz += __shfl_xor(fz, o);
  }
  if (lane == 0){
    out[1 + 3*a + 0] = fx;
    out[1 + 3*a + 1] = fy;
    out[1 + 3*a + 2] = fz;
  }
}

extern "C" void kernel_launch(void* const* d_in, const int* in_sizes, int n_in,
                              void* d_out, int out_size, void* d_ws, size_t ws_size,
                              hipStream_t stream){
  const float* pos   = (const float*)d_in[0];
  const int*   z     = (const int*)  d_in[1];
  const float* embed = (const float*)d_in[2];
  const float* W1    = (const float*)d_in[3];
  const float* W2    = (const float*)d_in[4];
  const float* Wr1   = (const float*)d_in[5];
  const float* Wr2   = (const float*)d_in[6];
  float* out = (float*)d_out;

  float* ws = (float*)d_ws;
  float* h0   = ws;            // NF
  float* h1   = h0 + NF;
  float* h2   = h1 + NF;
  float* m1   = h2 + NF;
  float* m2   = m1 + NF;
  float* g2b  = m2 + NF;
  float* g1b  = g2b + NF;
  float* Abuf = g1b + NF;      // NKF : A1, A2, Agg2
  float* Bbuf = Abuf + NKF;    // NKF : split partials / dA2 / dA1
  float* WT1  = Bbuf + NKF;    // KFF
  float* WT2  = WT1 + KFF;     // KFF
  float* WD2  = WT2 + KFF;     // KFF
  float* Wr1T = WD2 + KFF;     // FF
  float* e_at = Wr1T + FF;     // N
  float* nb_d = e_at + N_ATOMS;        // N*MAXNB
  float* edge_s = nb_d + N_ATOMS*MAXNB;// N*MAXNB
  int* nb_idx = (int*)(edge_s + N_ATOMS*MAXNB); // N*MAXNB
  int* nb_cnt = nb_idx + N_ATOMS*MAXNB;         // N

  k_nb<<<N_ATOMS, 64, 0, stream>>>(pos, nb_idx, nb_d, nb_cnt);
  k_embed<<<NF/256, 256, 0, stream>>>(z, embed, h0);
  k_wprep<<<KFF/256, 256, 0, stream>>>(W1, W2, Wr1, WT1, WT2, WD2, Wr1T);

  // forward layer 1
  k_agg<<<N_ATOMS, 256, 0, stream>>>(h0, nb_idx, nb_d, nb_cnt, Abuf);
  k_gemm_split<<<dim3(N_ATOMS/16, 4), 256, 0, stream>>>(Abuf, W1, Bbuf);
  k_reduce<<<NF4/256, 256, 0, stream>>>(Bbuf, h0, h0, m1, h1, 0);
  // forward layer 2
  k_agg<<<N_ATOMS, 256, 0, stream>>>(h1, nb_idx, nb_d, nb_cnt, Abuf);
  k_gemm_split<<<dim3(N_ATOMS/16, 4), 256, 0, stream>>>(Abuf, W2, Bbuf);
  k_reduce<<<NF4/256, 256, 0, stream>>>(Bbuf, h1, h1, m2, h2, 0);

  // readout + energy
  k_readout<<<N_ATOMS/8, 128, 0, stream>>>(h2, m2, Wr1, Wr1T, Wr2, e_at, g2b);
  k_esum<<<1, 256, 0, stream>>>(e_at, out);

  // backward
  k_gemm_bwd<<<dim3(N_ATOMS/64, 8), 256, 0, stream>>>(g2b, WT2, Bbuf);          // dA2
  k_edge<<<N_ATOMS, 256, 0, stream>>>(Bbuf, h1, nb_idx, nb_d, nb_cnt, edge_s, 0);
  k_agg<<<N_ATOMS, 256, 0, stream>>>(g2b, nb_idx, nb_d, nb_cnt, Abuf);          // Agg2
  k_gemm_split<<<dim3(N_ATOMS/16, 4), 256, 0, stream>>>(Abuf, WD2, Bbuf);
  k_reduce<<<NF4/256, 256, 0, stream>>>(Bbuf, g2b, m1, g1b, g1b, 1);            // g1
  k_gemm_bwd<<<dim3(N_ATOMS/64, 8), 256, 0, stream>>>(g1b, WT1, Bbuf);          // dA1
  k_edge<<<N_ATOMS, 256, 0, stream>>>(Bbuf, h0, nb_idx, nb_d, nb_cnt, edge_s, 1);
  k_force<<<N_ATOMS, 64, 0, stream>>>(pos, nb_idx, nb_d, nb_cnt, edge_s, out);
}

// Round 6
// 258.558 us; speedup vs baseline: 1.7823x; 1.2063x over previous
//
#include <hip/hip_runtime.h>
#include <math.h>

#define N_ATOMS 4096
#define F 128
#define K 8
#define KF 1024           // K*F
#define KFF 131072        // K*F*F
#define FF 16384          // F*F
#define NF 524288         // N*F
#define NF4 131072        // NF/4
#define NKF 4194304       // N*K*F
#define MAXNB 128
#define RMAX 5.0f
#define GAMMA 2.56f       // (K/RMAX)^2
#define MU_STEP 0.714285714285714f  // RMAX/(K-1)
#define PI_F 3.14159265358979323846f
#define POR (PI_F / RMAX)

typedef __bf16 bf16x8_t __attribute__((ext_vector_type(8)));
typedef float f32x4_t __attribute__((ext_vector_type(4)));
typedef unsigned short u16x8_t __attribute__((ext_vector_type(8)));

__device__ __forceinline__ float sigm(float x){ return 1.0f/(1.0f + expf(-x)); }
__device__ __forceinline__ unsigned short f2bf(float x){
  unsigned int u = __float_as_uint(x);
  u += 0x7fff + ((u >> 16) & 1);
  return (unsigned short)(u >> 16);
}

// ---------------- neighbor list (deterministic ballot compaction) -----------
__global__ __launch_bounds__(64) void k_nb(const float* __restrict__ pos,
        int* __restrict__ nb_idx, float* __restrict__ nb_d, int* __restrict__ nb_cnt){
  int i = blockIdx.x;
  int lane = threadIdx.x;
  float pix = pos[3*i], piy = pos[3*i+1], piz = pos[3*i+2];
  float sqi = pix*pix + piy*piy + piz*piz;
  int count = 0;
  for (int jb = 0; jb < N_ATOMS; jb += 64){
    int j = jb + lane;
    float pjx = pos[3*j], pjy = pos[3*j+1], pjz = pos[3*j+2];
    float sqj = pjx*pjx + pjy*pjy + pjz*pjz;
    float dot = pix*pjx + piy*pjy + piz*pjz;
    float d2 = sqi + sqj - 2.0f*dot;
    float d = sqrtf(d2);
    bool pred = (j != i) && (d2 > 0.0f) && (d < RMAX);
    unsigned long long m = __ballot(pred);
    int off = __popcll(m & ((1ull << lane) - 1ull));
    if (pred){
      int p = count + off;
      if (p < MAXNB){ nb_idx[i*MAXNB + p] = j; nb_d[i*MAXNB + p] = d; }
    }
    count += __popcll(m);
  }
  if (lane == 0) nb_cnt[i] = count > MAXNB ? MAXNB : count;
}

// ---------------- h0 = embed[z] ---------------------------------------------
__global__ __launch_bounds__(256) void k_embed(const int* __restrict__ z,
        const float* __restrict__ embed, float* __restrict__ h0){
  int idx = blockIdx.x*256 + threadIdx.x;
  int i = idx >> 7, f = idx & 127;
  h0[idx] = embed[z[i]*F + f];
}

// ---------------- weight prep: bf16 MFMA fragment layouts -------------------
// fwd B-frag (K=1024, N=128): flat = ((kc*8+nt)*64+l)*8+j
//   kf = kc*32 + ((l>>4)&3)*8 + j ; g = nt*16 + (l&15)
// bwd B-frag (K=128, N=1024): flat = ((kc*64+nt)*64+l)*8+j
//   g  = kc*32 + ((l>>4)&3)*8 + j ; kf = nt*16 + (l&15)
__global__ __launch_bounds__(256) void k_wprep(const float* __restrict__ W1,
        const float* __restrict__ W2, const float* __restrict__ Wr1,
        unsigned short* __restrict__ WF1, unsigned short* __restrict__ WF2,
        unsigned short* __restrict__ WDF2, unsigned short* __restrict__ WTF1,
        unsigned short* __restrict__ WTF2, float* __restrict__ Wr1T){
  int idx = blockIdx.x*256 + threadIdx.x;   // 0..16383
  int l = idx & 63;
  int hi = idx >> 6;
  {
    // fwd frags
    int kc = hi >> 3, nt = hi & 7;
    int kfb = kc*32 + ((l>>4)&3)*8;
    int g = nt*16 + (l&15);
    u16x8_t v1, v2, vd;
    #pragma unroll
    for (int j = 0; j < 8; j++){
      int kf = kfb + j;
      v1[j] = f2bf(W1[kf*128 + g]);
      v2[j] = f2bf(W2[kf*128 + g]);
      vd[j] = f2bf(W2[(kf>>7)*FF + g*F + (kf&127)]);
    }
    *(u16x8_t*)(WF1 + idx*8) = v1;
    *(u16x8_t*)(WF2 + idx*8) = v2;
    *(u16x8_t*)(WDF2 + idx*8) = vd;
  }
  {
    // bwd frags
    int kc = hi >> 6, nt = hi & 63;
    int gb = kc*32 + ((l>>4)&3)*8;
    int kf = nt*16 + (l&15);
    u16x8_t t1, t2;
    #pragma unroll
    for (int j = 0; j < 8; j++){
      int g = gb + j;
      t1[j] = f2bf(W1[kf*128 + g]);
      t2[j] = f2bf(W2[kf*128 + g]);
    }
    *(u16x8_t*)(WTF1 + idx*8) = t1;
    *(u16x8_t*)(WTF2 + idx*8) = t2;
  }
  {
    int f = idx >> 7, g = idx & 127;
    Wr1T[idx] = Wr1[g*F + f];
  }
}

// ---- A[a,kf] = sum_n rbf_k(d_an) h[j_n,f], written as bf16 A-fragments -----
// A-frag flat = ((atile*32 + kc)*64 + l)*8 + j
//   atile=a>>4, kc = k*4+(f>>5), l = (a&15)|(((f>>3)&3)<<4), j = f&7
__global__ __launch_bounds__(256) void k_agg(const float* __restrict__ h_in,
        const int* __restrict__ nb_idx, const float* __restrict__ nb_d,
        const int* __restrict__ nb_cnt, unsigned short* __restrict__ Af){
  int a = blockIdx.x;
  int t = threadIdx.x;
  int f = t & 127;
  int kq = (t >> 7) * 4;
  __shared__ float s_rbf[MAXNB][8];
  __shared__ int s_j[MAXNB];
  int cnt = nb_cnt[a];
  for (int idx = t; idx < cnt*8; idx += 256){
    int n = idx >> 3, k = idx & 7;
    float d = nb_d[a*MAXNB + n];
    float dm = d - MU_STEP*(float)k;
    float env = 0.5f*(cosf(POR*d) + 1.0f);
    s_rbf[n][k] = expf(-GAMMA*dm*dm)*env;
  }
  for (int idx = t; idx < cnt; idx += 256) s_j[idx] = nb_idx[a*MAXNB + idx];
  __syncthreads();
  float a0=0.f, a1=0.f, a2=0.f, a3=0.f;
  int n = 0;
  for (; n + 2 <= cnt; n += 2){
    float hv0 = h_in[s_j[n]*F + f];
    float hv1 = h_in[s_j[n+1]*F + f];
    float4 r0 = *(const float4*)&s_rbf[n][kq];
    float4 r1 = *(const float4*)&s_rbf[n+1][kq];
    a0 += r0.x*hv0 + r1.x*hv1;
    a1 += r0.y*hv0 + r1.y*hv1;
    a2 += r0.z*hv0 + r1.z*hv1;
    a3 += r0.w*hv0 + r1.w*hv1;
  }
  if (n < cnt){
    float hv0 = h_in[s_j[n]*F + f];
    float4 r0 = *(const float4*)&s_rbf[n][kq];
    a0 += r0.x*hv0; a1 += r0.y*hv0; a2 += r0.z*hv0; a3 += r0.w*hv0;
  }
  int lf = (a & 15) | (((f >> 3) & 3) << 4);
  int j = f & 7;
  size_t base = (size_t)(a >> 4) * 16384 + lf*8 + j;
  int f5 = f >> 5;
  Af[base + ((kq+0)*4 + f5)*512] = f2bf(a0);
  Af[base + ((kq+1)*4 + f5)*512] = f2bf(a1);
  Af[base + ((kq+2)*4 + f5)*512] = f2bf(a2);
  Af[base + ((kq+3)*4 + f5)*512] = f2bf(a3);
}

// ---- g (f32 [4096][128]) -> bf16 A-frag (K=128): flat=((atile*4+kc)*64+l)*8+j
__global__ __launch_bounds__(256) void k_g2frag(const float* __restrict__ g,
        unsigned short* __restrict__ Gf){
  int idx = blockIdx.x*256 + threadIdx.x;    // 65536
  int a = idx >> 4, oct = idx & 15;
  const float4* s = (const float4*)(g + a*128 + oct*8);
  float4 v0 = s[0], v1 = s[1];
  int kc = oct >> 2, l = (a & 15) | ((oct & 3) << 4);
  u16x8_t o;
  o[0]=f2bf(v0.x); o[1]=f2bf(v0.y); o[2]=f2bf(v0.z); o[3]=f2bf(v0.w);
  o[4]=f2bf(v1.x); o[5]=f2bf(v1.y); o[6]=f2bf(v1.z); o[7]=f2bf(v1.w);
  *(u16x8_t*)(Gf + (((size_t)(a>>4)*4 + kc)*64 + l)*8) = o;
}

// ---- MFMA GEMM fwd-shape: part[sl][i][g] = sum_{kf slice} A[i,kf] W[kf,g] --
// grid (64, 8), 256 thr (4 waves), wave = 16 rows x 128 cols, K-slice 128.
__global__ __launch_bounds__(256) void k_mgemm_fwd(const unsigned short* __restrict__ Af,
        const unsigned short* __restrict__ Bf, float* __restrict__ part){
  int t = threadIdx.x;
  int l = t & 63, w = t >> 6;
  int rtile = blockIdx.x*4 + w;
  int kc0 = blockIdx.y*4;
  f32x4_t acc[8];
  #pragma unroll
  for (int i = 0; i < 8; i++) acc[i] = (f32x4_t){0.f,0.f,0.f,0.f};
  const unsigned short* Ab = Af + (size_t)rtile*16384 + l*8;
  const unsigned short* Bb = Bf + l*8;
  #pragma unroll
  for (int ki = 0; ki < 4; ki++){
    int kc = kc0 + ki;
    bf16x8_t a = *(const bf16x8_t*)(Ab + kc*512);
    #pragma unroll
    for (int nt = 0; nt < 8; nt++){
      bf16x8_t b = *(const bf16x8_t*)(Bb + (kc*8 + nt)*512);
      acc[nt] = __builtin_amdgcn_mfma_f32_16x16x32_bf16(a, b, acc[nt], 0, 0, 0);
    }
  }
  float* p = part + (size_t)blockIdx.y*NF;
  int row0 = rtile*16 + (l >> 4)*4;
  int col = l & 15;
  #pragma unroll
  for (int nt = 0; nt < 8; nt++){
    #pragma unroll
    for (int r = 0; r < 4; r++)
      p[(row0+r)*128 + nt*16 + col] = acc[nt][r];
  }
}

// ---- MFMA GEMM bwd-shape: dA[i,kf] = sum_g G[i,g] WT[g,kf] -----------------
// grid (64, 8), 256 thr; wave = 16 rows x 128 cols of the 1024-wide output.
__global__ __launch_bounds__(256) void k_mgemm_bwd(const unsigned short* __restrict__ Gf,
        const unsigned short* __restrict__ Bf, float* __restrict__ dA){
  int t = threadIdx.x;
  int l = t & 63, w = t >> 6;
  int rtile = blockIdx.x*4 + w;
  int nt0 = blockIdx.y*8;
  f32x4_t acc[8];
  #pragma unroll
  for (int i = 0; i < 8; i++) acc[i] = (f32x4_t){0.f,0.f,0.f,0.f};
  const unsigned short* Ab = Gf + (size_t)rtile*2048 + l*8;
  const unsigned short* Bb = Bf + l*8;
  #pragma unroll
  for (int kc = 0; kc < 4; kc++){
    bf16x8_t a = *(const bf16x8_t*)(Ab + kc*512);
    #pragma unroll
    for (int nt = 0; nt < 8; nt++){
      bf16x8_t b = *(const bf16x8_t*)(Bb + (kc*64 + nt0 + nt)*512);
      acc[nt] = __builtin_amdgcn_mfma_f32_16x16x32_bf16(a, b, acc[nt], 0, 0, 0);
    }
  }
  int row0 = rtile*16 + (l >> 4)*4;
  int col = l & 15;
  #pragma unroll
  for (int nt = 0; nt < 8; nt++){
    #pragma unroll
    for (int r = 0; r < 4; r++)
      dA[(size_t)(row0+r)*1024 + (nt0+nt)*16 + col] = acc[nt][r];
  }
}

// ------- reduce 8 split-K partials + epilogue -------------------------------
// mode 0: m = sum + addv; out_m = m; out_h = silu(m)
// mode 1: out_h = (sum + addv) * silu'(msrc)
__global__ __launch_bounds__(256) void k_reduce(const float* __restrict__ part,
        const float* __restrict__ addv, const float* __restrict__ msrc,
        float* __restrict__ out_m, float* __restrict__ out_h, int mode){
  int idx = blockIdx.x*256 + threadIdx.x;
  const float4* p = (const float4*)part;
  float4 s = p[idx];
  #pragma unroll
  for (int sl = 1; sl < 8; sl++){
    float4 b = p[idx + sl*NF4];
    s.x += b.x; s.y += b.y; s.z += b.z; s.w += b.w;
  }
  float4 av = ((const float4*)addv)[idx];
  s.x += av.x; s.y += av.y; s.z += av.z; s.w += av.w;
  if (mode == 0){
    ((float4*)out_m)[idx] = s;
    float4 o;
    o.x = s.x*sigm(s.x); o.y = s.y*sigm(s.y); o.z = s.z*sigm(s.z); o.w = s.w*sigm(s.w);
    ((float4*)out_h)[idx] = o;
  } else {
    float4 mm = ((const float4*)msrc)[idx];
    float4 o; float sg;
    sg = sigm(mm.x); o.x = s.x*(sg*(1.f+mm.x*(1.f-sg)));
    sg = sigm(mm.y); o.y = s.y*(sg*(1.f+mm.y*(1.f-sg)));
    sg = sigm(mm.z); o.z = s.z*(sg*(1.f+mm.z*(1.f-sg)));
    sg = sigm(mm.w); o.w = s.w*(sg*(1.f+mm.w*(1.f-sg)));
    ((float4*)out_h)[idx] = o;
  }
}

// ---------------- readout fwd + bwd: e_atom, g2 = dE/dm2 --------------------
__global__ __launch_bounds__(128) void k_readout(const float* __restrict__ h2,
        const float* __restrict__ m2, const float* __restrict__ Wr1,
        const float* __restrict__ Wr1T, const float* __restrict__ Wr2,
        float* __restrict__ e_at, float* __restrict__ g2){
  int b = blockIdx.x * 8;
  int t = threadIdx.x;
  int lane = t & 63, wv = t >> 6;
  __shared__ float sh[128][8];
  __shared__ float sdu[128][8];
  __shared__ float red[2][8];
  #pragma unroll
  for (int r = 0; r < 8; r++) sh[t][r] = h2[(b+r)*F + t];
  __syncthreads();
  float u[8] = {0,0,0,0,0,0,0,0};
  for (int g = 0; g < 128; g++){
    float wvv = Wr1[g*F + t];
    float4 s0 = *(const float4*)&sh[g][0];
    float4 s1 = *(const float4*)&sh[g][4];
    u[0] += s0.x*wvv; u[1] += s0.y*wvv; u[2] += s0.z*wvv; u[3] += s0.w*wvv;
    u[4] += s1.x*wvv; u[5] += s1.y*wvv; u[6] += s1.z*wvv; u[7] += s1.w*wvv;
  }
  float w2 = Wr2[t];
  #pragma unroll
  for (int r = 0; r < 8; r++){
    float sg = sigm(u[r]);
    float e = u[r]*sg*w2;
    #pragma unroll
    for (int o = 1; o < 64; o <<= 1) e += __shfl_xor(e, o);
    if (lane == 0) red[wv][r] = e;
    sdu[t][r] = w2*(sg*(1.f + u[r]*(1.f - sg)));
  }
  __syncthreads();
  if (t < 8) e_at[b+t] = red[0][t] + red[1][t];
  float dh[8] = {0,0,0,0,0,0,0,0};
  for (int f = 0; f < 128; f++){
    float wvv = Wr1T[f*F + t];
    float4 s0 = *(const float4*)&sdu[f][0];
    float4 s1 = *(const float4*)&sdu[f][4];
    dh[0] += s0.x*wvv; dh[1] += s0.y*wvv; dh[2] += s0.z*wvv; dh[3] += s0.w*wvv;
    dh[4] += s1.x*wvv; dh[5] += s1.y*wvv; dh[6] += s1.z*wvv; dh[7] += s1.w*wvv;
  }
  #pragma unroll
  for (int r = 0; r < 8; r++){
    float mm = m2[(b+r)*F + t];
    float sg = sigm(mm);
    g2[(b+r)*F + t] = dh[r]*(sg*(1.f + mm*(1.f - sg)));
  }
}

// ---------------- deterministic energy sum ----------------------------------
__global__ __launch_bounds__(256) void k_esum(const float* __restrict__ e_at,
        float* __restrict__ out){
  __shared__ float red[256];
  float s = 0.f;
  for (int i = threadIdx.x; i < N_ATOMS; i += 256) s += e_at[i];
  red[threadIdx.x] = s;
  __syncthreads();
  for (int o = 128; o > 0; o >>= 1){
    if (threadIdx.x < o) red[threadIdx.x] += red[threadIdx.x + o];
    __syncthreads();
  }
  if (threadIdx.x == 0) out[0] = red[0];
}

// ------- per-edge scalar, one dA/h pair per pass ----------------------------
__global__ __launch_bounds__(256) void k_edge(const float* __restrict__ dA,
        const float* __restrict__ h,
        const int* __restrict__ nb_idx, const float* __restrict__ nb_d,
        const int* __restrict__ nb_cnt, float* __restrict__ edge_s, int accum){
  int a = blockIdx.x;
  int t = threadIdx.x;
  int lane = t & 63, w = t >> 6;
  __shared__ float sdr[MAXNB][8];
  __shared__ int s_j[MAXNB];
  int cnt = nb_cnt[a];
  for (int idx = t; idx < cnt*8; idx += 256){
    int n = idx >> 3, k = idx & 7;
    float d = nb_d[a*MAXNB + n];
    float dm = d - MU_STEP*(float)k;
    float G = expf(-GAMMA*dm*dm);
    float ph = POR*d;
    float env = 0.5f*(cosf(ph) + 1.0f);
    float denv = -0.5f*POR*sinf(ph);
    sdr[n][k] = G*(-2.0f*GAMMA*dm*env + denv);
  }
  for (int idx = t; idx < cnt; idx += 256) s_j[idx] = nb_idx[a*MAXNB + idx];
  float2 ar[8];
  #pragma unroll
  for (int k = 0; k < 8; k++)
    ar[k] = *(const float2*)&dA[(size_t)a*KF + k*F + 2*lane];
  __syncthreads();
  for (int n = w; n < cnt; n += 4){
    int j = s_j[n];
    float2 hv = *(const float2*)&h[j*F + 2*lane];
    float part = 0.f;
    #pragma unroll
    for (int k = 0; k < 8; k++)
      part += sdr[n][k]*(ar[k].x*hv.x + ar[k].y*hv.y);
    #pragma unroll
    for (int o = 1; o < 64; o <<= 1) part += __shfl_xor(part, o);
    if (lane == 0){
      if (accum) edge_s[a*MAXNB + n] += part;
      else       edge_s[a*MAXNB + n]  = part;
    }
  }
}

// ------- force: F_a = -sum_j (s_aj + s_ja) * (pa-pj)/d ----------------------
__global__ __launch_bounds__(64) void k_force(const float* __restrict__ pos,
        const int* __restrict__ nb_idx, const float* __restrict__ nb_d,
        const int* __restrict__ nb_cnt, const float* __restrict__ edge_s,
        float* __restrict__ out){
  int a = blockIdx.x;
  int lane = threadIdx.x;
  float pax = pos[3*a], pay = pos[3*a+1], paz = pos[3*a+2];
  int cnt = nb_cnt[a];
  float fx = 0.f, fy = 0.f, fz = 0.f;
  for (int n = lane; n < cnt; n += 64){
    int j = nb_idx[a*MAXNB + n];
    float d = nb_d[a*MAXNB + n];
    float s = edge_s[a*MAXNB + n];
    int cj = nb_cnt[j];
    int lo = 0, hi = cj - 1, p = -1;
    while (lo <= hi){
      int mid = (lo + hi) >> 1;
      int v = nb_idx[j*MAXNB + mid];
      if (v == a){ p = mid; break; }
      if (v < a) lo = mid + 1; else hi = mid - 1;
    }
    float sj = (p >= 0) ? edge_s[j*MAXNB + p] : 0.0f;
    float coef = (s + sj)/d;
    float dx = pax - pos[3*j], dy = pay - pos[3*j+1], dz = paz - pos[3*j+2];
    fx -= coef*dx; fy -= coef*dy; fz -= coef*dz;
  }
  #pragma unroll
  for (int o = 1; o < 64; o <<= 1){
    fx += __shfl_xor(fx, o); fy += __shfl_xor(fy, o); fz += __shfl_xor(fz, o);
  }
  if (lane == 0){
    out[1 + 3*a + 0] = fx;
    out[1 + 3*a + 1] = fy;
    out[1 + 3*a + 2] = fz;
  }
}

extern "C" void kernel_launch(void* const* d_in, const int* in_sizes, int n_in,
                              void* d_out, int out_size, void* d_ws, size_t ws_size,
                              hipStream_t stream){
  const float* pos   = (const float*)d_in[0];
  const int*   z     = (const int*)  d_in[1];
  const float* embed = (const float*)d_in[2];
  const float* W1    = (const float*)d_in[3];
  const float* W2    = (const float*)d_in[4];
  const float* Wr1   = (const float*)d_in[5];
  const float* Wr2   = (const float*)d_in[6];
  float* out = (float*)d_out;

  float* ws = (float*)d_ws;
  float* h0   = ws;            // NF
  float* h1   = h0 + NF;
  float* h2   = h1 + NF;
  float* m1   = h2 + NF;
  float* m2   = m1 + NF;
  float* g2b  = m2 + NF;
  float* g1b  = g2b + NF;
  float* Bbuf = g1b + NF;      // NKF f32: split partials / dA2 / dA1
  unsigned short* Afrag = (unsigned short*)(Bbuf + NKF);  // NKF bf16
  unsigned short* Gfrag = Afrag + NKF;                    // NF bf16
  unsigned short* WF1  = Gfrag + NF;   // KFF bf16 each
  unsigned short* WF2  = WF1 + KFF;
  unsigned short* WDF2 = WF2 + KFF;
  unsigned short* WTF1 = WDF2 + KFF;
  unsigned short* WTF2 = WTF1 + KFF;
  float* Wr1T = (float*)(WTF2 + KFF);  // FF
  float* e_at = Wr1T + FF;             // N
  float* nb_d = e_at + N_ATOMS;        // N*MAXNB
  float* edge_s = nb_d + N_ATOMS*MAXNB;// N*MAXNB
  int* nb_idx = (int*)(edge_s + N_ATOMS*MAXNB); // N*MAXNB
  int* nb_cnt = nb_idx + N_ATOMS*MAXNB;         // N

  k_nb<<<N_ATOMS, 64, 0, stream>>>(pos, nb_idx, nb_d, nb_cnt);
  k_embed<<<NF/256, 256, 0, stream>>>(z, embed, h0);
  k_wprep<<<64, 256, 0, stream>>>(W1, W2, Wr1, WF1, WF2, WDF2, WTF1, WTF2, Wr1T);

  // forward layer 1
  k_agg<<<N_ATOMS, 256, 0, stream>>>(h0, nb_idx, nb_d, nb_cnt, Afrag);
  k_mgemm_fwd<<<dim3(64, 8), 256, 0, stream>>>(Afrag, WF1, Bbuf);
  k_reduce<<<NF4/256, 256, 0, stream>>>(Bbuf, h0, h0, m1, h1, 0);
  // forward layer 2
  k_agg<<<N_ATOMS, 256, 0, stream>>>(h1, nb_idx, nb_d, nb_cnt, Afrag);
  k_mgemm_fwd<<<dim3(64, 8), 256, 0, stream>>>(Afrag, WF2, Bbuf);
  k_reduce<<<NF4/256, 256, 0, stream>>>(Bbuf, h1, h1, m2, h2, 0);

  // readout + energy
  k_readout<<<N_ATOMS/8, 128, 0, stream>>>(h2, m2, Wr1, Wr1T, Wr2, e_at, g2b);
  k_esum<<<1, 256, 0, stream>>>(e_at, out);

  // backward
  k_g2frag<<<256, 256, 0, stream>>>(g2b, Gfrag);
  k_mgemm_bwd<<<dim3(64, 8), 256, 0, stream>>>(Gfrag, WTF2, Bbuf);        // dA2
  k_edge<<<N_ATOMS, 256, 0, stream>>>(Bbuf, h1, nb_idx, nb_d, nb_cnt, edge_s, 0);
  k_agg<<<N_ATOMS, 256, 0, stream>>>(g2b, nb_idx, nb_d, nb_cnt, Afrag);   // Agg2
  k_mgemm_fwd<<<dim3(64, 8), 256, 0, stream>>>(Afrag, WDF2, Bbuf);
  k_reduce<<<NF4/256, 256, 0, stream>>>(Bbuf, g2b, m1, g1b, g1b, 1);      // g1
  k_g2frag<<<256, 256, 0, stream>>>(g1b, Gfrag);
  k_mgemm_bwd<<<dim3(64, 8), 256, 0, stream>>>(Gfrag, WTF1, Bbuf);        // dA1
  k_edge<<<N_ATOMS, 256, 0, stream>>>(Bbuf, h0, nb_idx, nb_d, nb_cnt, edge_s, 1);
  k_force<<<N_ATOMS, 64, 0, stream>>>(pos, nb_idx, nb_d, nb_cnt, edge_s, out);
}

// Round 7
// 233.039 us; speedup vs baseline: 1.9775x; 1.1095x over previous
//
#include <hip/hip_runtime.h>
#include <math.h>

#define N_ATOMS 4096
#define F 128
#define K 8
#define KF 1024           // K*F
#define KFF 131072        // K*F*F
#define FF 16384          // F*F
#define NF 524288         // N*F
#define NF4 131072        // NF/4
#define NKF 4194304       // N*K*F
#define MAXNB 128
#define RMAX 5.0f
#define GAMMA 2.56f       // (K/RMAX)^2
#define MU_STEP 0.714285714285714f  // RMAX/(K-1)
#define PI_F 3.14159265358979323846f
#define POR (PI_F / RMAX)

typedef __bf16 bf16x8_t __attribute__((ext_vector_type(8)));
typedef float f32x4_t __attribute__((ext_vector_type(4)));
typedef unsigned short u16x8_t __attribute__((ext_vector_type(8)));
typedef unsigned short u16x4_t __attribute__((ext_vector_type(4)));

__device__ __forceinline__ float sigm(float x){ return 1.0f/(1.0f + expf(-x)); }
__device__ __forceinline__ unsigned short f2bf(float x){
  unsigned int u = __float_as_uint(x);
  u += 0x7fff + ((u >> 16) & 1);
  return (unsigned short)(u >> 16);
}

// ---------------- neighbor list: 4 atoms/block, LDS-tiled j scan ------------
__global__ __launch_bounds__(256) void k_nb(const float* __restrict__ pos,
        int* __restrict__ nb_idx, float* __restrict__ nb_d, int* __restrict__ nb_cnt){
  int t = threadIdx.x;
  int w = t >> 6, lane = t & 63;
  int i = blockIdx.x*4 + w;
  __shared__ float spx[256], spy[256], spz[256], ssq[256];
  float pix = pos[3*i], piy = pos[3*i+1], piz = pos[3*i+2];
  float sqi = pix*pix + piy*piy + piz*piz;
  int count = 0;
  for (int jb = 0; jb < N_ATOMS; jb += 256){
    __syncthreads();
    float px = pos[3*(jb+t)], py = pos[3*(jb+t)+1], pz = pos[3*(jb+t)+2];
    spx[t] = px; spy[t] = py; spz[t] = pz;
    ssq[t] = px*px + py*py + pz*pz;
    __syncthreads();
    #pragma unroll
    for (int c = 0; c < 4; c++){
      int jj = c*64 + lane;
      int j = jb + jj;
      float dot = pix*spx[jj] + piy*spy[jj] + piz*spz[jj];
      float d2 = sqi + ssq[jj] - 2.0f*dot;
      float d = sqrtf(d2);
      bool pred = (j != i) && (d2 > 0.0f) && (d < RMAX);
      unsigned long long m = __ballot(pred);
      int off = __popcll(m & ((1ull << lane) - 1ull));
      if (pred){
        int p = count + off;
        if (p < MAXNB){ nb_idx[i*MAXNB + p] = j; nb_d[i*MAXNB + p] = d; }
      }
      count += __popcll(m);
    }
  }
  if (lane == 0) nb_cnt[i] = count > MAXNB ? MAXNB : count;
}

// ---------------- h0 = embed[z] ---------------------------------------------
__global__ __launch_bounds__(256) void k_embed(const int* __restrict__ z,
        const float* __restrict__ embed, float* __restrict__ h0){
  int idx = blockIdx.x*256 + threadIdx.x;
  int i = idx >> 7, f = idx & 127;
  h0[idx] = embed[z[i]*F + f];
}

// ---------------- weight prep: bf16 MFMA fragment layouts -------------------
__global__ __launch_bounds__(256) void k_wprep(const float* __restrict__ W1,
        const float* __restrict__ W2, const float* __restrict__ Wr1,
        unsigned short* __restrict__ WF1, unsigned short* __restrict__ WF2,
        unsigned short* __restrict__ WDF2, unsigned short* __restrict__ WTF1,
        unsigned short* __restrict__ WTF2, float* __restrict__ Wr1T){
  int idx = blockIdx.x*256 + threadIdx.x;   // 0..16383
  int l = idx & 63;
  int hi = idx >> 6;
  {
    int kc = hi >> 3, nt = hi & 7;
    int kfb = kc*32 + ((l>>4)&3)*8;
    int g = nt*16 + (l&15);
    u16x8_t v1, v2, vd;
    #pragma unroll
    for (int j = 0; j < 8; j++){
      int kf = kfb + j;
      v1[j] = f2bf(W1[kf*128 + g]);
      v2[j] = f2bf(W2[kf*128 + g]);
      vd[j] = f2bf(W2[(kf>>7)*FF + g*F + (kf&127)]);
    }
    *(u16x8_t*)(WF1 + idx*8) = v1;
    *(u16x8_t*)(WF2 + idx*8) = v2;
    *(u16x8_t*)(WDF2 + idx*8) = vd;
  }
  {
    int kc = hi >> 6, nt = hi & 63;
    int gb = kc*32 + ((l>>4)&3)*8;
    int kf = nt*16 + (l&15);
    u16x8_t t1, t2;
    #pragma unroll
    for (int j = 0; j < 8; j++){
      int g = gb + j;
      t1[j] = f2bf(W1[kf*128 + g]);
      t2[j] = f2bf(W2[kf*128 + g]);
    }
    *(u16x8_t*)(WTF1 + idx*8) = t1;
    *(u16x8_t*)(WTF2 + idx*8) = t2;
  }
  {
    int f = idx >> 7, g = idx & 127;
    Wr1T[idx] = Wr1[g*F + f];
  }
}

// ---- A[a,k,f] = sum_n rbf_k(d_an) h[j_n,f] -> bf16 A-fragments -------------
// 4 waves split neighbors (n % 4), float2 loads, LDS cross-wave reduce.
__global__ __launch_bounds__(256) void k_agg(const float* __restrict__ h_in,
        const int* __restrict__ nb_idx, const float* __restrict__ nb_d,
        const int* __restrict__ nb_cnt, unsigned short* __restrict__ Af){
  int a = blockIdx.x;
  int t = threadIdx.x;
  int grp = t >> 6, lane = t & 63;
  __shared__ float s_rbf[MAXNB][8];
  __shared__ int s_j[MAXNB];
  __shared__ float s_acc[4][8][128];
  int cnt = nb_cnt[a];
  for (int idx = t; idx < cnt*8; idx += 256){
    int n = idx >> 3, k = idx & 7;
    float d = nb_d[a*MAXNB + n];
    float dm = d - MU_STEP*(float)k;
    float env = 0.5f*(cosf(POR*d) + 1.0f);
    s_rbf[n][k] = expf(-GAMMA*dm*dm)*env;
  }
  for (int idx = t; idx < cnt; idx += 256) s_j[idx] = nb_idx[a*MAXNB + idx];
  __syncthreads();
  float2 acc[8];
  #pragma unroll
  for (int k = 0; k < 8; k++) acc[k] = {0.f, 0.f};
  for (int n = grp; n < cnt; n += 4){
    float2 hv = *(const float2*)&h_in[(size_t)s_j[n]*F + lane*2];
    float4 r0 = *(const float4*)&s_rbf[n][0];
    float4 r1 = *(const float4*)&s_rbf[n][4];
    acc[0].x += r0.x*hv.x; acc[0].y += r0.x*hv.y;
    acc[1].x += r0.y*hv.x; acc[1].y += r0.y*hv.y;
    acc[2].x += r0.z*hv.x; acc[2].y += r0.z*hv.y;
    acc[3].x += r0.w*hv.x; acc[3].y += r0.w*hv.y;
    acc[4].x += r1.x*hv.x; acc[4].y += r1.x*hv.y;
    acc[5].x += r1.y*hv.x; acc[5].y += r1.y*hv.y;
    acc[6].x += r1.z*hv.x; acc[6].y += r1.z*hv.y;
    acc[7].x += r1.w*hv.x; acc[7].y += r1.w*hv.y;
  }
  #pragma unroll
  for (int k = 0; k < 8; k++)
    *(float2*)&s_acc[grp][k][lane*2] = acc[k];
  __syncthreads();
  // reduce across 4 groups + write frags: thread t -> k = t>>5, f = (t&31)*4 + i
  int k = t >> 5, q = t & 31;
  int f0 = q*4;
  float v[4];
  #pragma unroll
  for (int i = 0; i < 4; i++){
    int f = f0 + i;
    v[i] = s_acc[0][k][f] + s_acc[1][k][f] + s_acc[2][k][f] + s_acc[3][k][f];
  }
  int lf = (a & 15) | (((f0 >> 3) & 3) << 4);
  int kc = k*4 + (f0 >> 5);
  size_t flat = (size_t)(a >> 4)*16384 + ((size_t)kc*64 + lf)*8 + (f0 & 7);
  u16x4_t o;
  o[0] = f2bf(v[0]); o[1] = f2bf(v[1]); o[2] = f2bf(v[2]); o[3] = f2bf(v[3]);
  *(u16x4_t*)(Af + flat) = o;
}

// ---- MFMA GEMM fwd-shape: part[sl][i][g] = sum_{kf slice} A[i,kf] W[kf,g] --
__global__ __launch_bounds__(256) void k_mgemm_fwd(const unsigned short* __restrict__ Af,
        const unsigned short* __restrict__ Bf, float* __restrict__ part){
  int t = threadIdx.x;
  int l = t & 63, w = t >> 6;
  int rtile = blockIdx.x*4 + w;
  int kc0 = blockIdx.y*4;
  f32x4_t acc[8];
  #pragma unroll
  for (int i = 0; i < 8; i++) acc[i] = (f32x4_t){0.f,0.f,0.f,0.f};
  const unsigned short* Ab = Af + (size_t)rtile*16384 + l*8;
  const unsigned short* Bb = Bf + l*8;
  #pragma unroll
  for (int ki = 0; ki < 4; ki++){
    int kc = kc0 + ki;
    bf16x8_t a = *(const bf16x8_t*)(Ab + kc*512);
    #pragma unroll
    for (int nt = 0; nt < 8; nt++){
      bf16x8_t b = *(const bf16x8_t*)(Bb + (kc*8 + nt)*512);
      acc[nt] = __builtin_amdgcn_mfma_f32_16x16x32_bf16(a, b, acc[nt], 0, 0, 0);
    }
  }
  float* p = part + (size_t)blockIdx.y*NF;
  int row0 = rtile*16 + (l >> 4)*4;
  int col = l & 15;
  #pragma unroll
  for (int nt = 0; nt < 8; nt++){
    #pragma unroll
    for (int r = 0; r < 4; r++)
      p[(row0+r)*128 + nt*16 + col] = acc[nt][r];
  }
}

// ---- MFMA GEMM bwd-shape: dA[i,kf] = sum_g G[i,g] WT[g,kf] -----------------
__global__ __launch_bounds__(256) void k_mgemm_bwd(const unsigned short* __restrict__ Gf,
        const unsigned short* __restrict__ Bf, float* __restrict__ dA){
  int t = threadIdx.x;
  int l = t & 63, w = t >> 6;
  int rtile = blockIdx.x*4 + w;
  int nt0 = blockIdx.y*8;
  f32x4_t acc[8];
  #pragma unroll
  for (int i = 0; i < 8; i++) acc[i] = (f32x4_t){0.f,0.f,0.f,0.f};
  const unsigned short* Ab = Gf + (size_t)rtile*2048 + l*8;
  const unsigned short* Bb = Bf + l*8;
  #pragma unroll
  for (int kc = 0; kc < 4; kc++){
    bf16x8_t a = *(const bf16x8_t*)(Ab + kc*512);
    #pragma unroll
    for (int nt = 0; nt < 8; nt++){
      bf16x8_t b = *(const bf16x8_t*)(Bb + (kc*64 + nt0 + nt)*512);
      acc[nt] = __builtin_amdgcn_mfma_f32_16x16x32_bf16(a, b, acc[nt], 0, 0, 0);
    }
  }
  int row0 = rtile*16 + (l >> 4)*4;
  int col = l & 15;
  #pragma unroll
  for (int nt = 0; nt < 8; nt++){
    #pragma unroll
    for (int r = 0; r < 4; r++)
      dA[(size_t)(row0+r)*1024 + (nt0+nt)*16 + col] = acc[nt][r];
  }
}

// ------- reduce 8 split-K partials + epilogue -------------------------------
// mode 0: m = sum + addv; out_m = m; out_h = silu(m)
// mode 1: g1 = (sum + addv) * silu'(msrc), written directly as bf16 A-frags
__global__ __launch_bounds__(256) void k_reduce(const float* __restrict__ part,
        const float* __restrict__ addv, const float* __restrict__ msrc,
        float* __restrict__ out_m, float* __restrict__ out_h,
        unsigned short* __restrict__ out_frag, int mode){
  int idx = blockIdx.x*256 + threadIdx.x;
  const float4* p = (const float4*)part;
  float4 s = p[idx];
  #pragma unroll
  for (int sl = 1; sl < 8; sl++){
    float4 b = p[idx + sl*NF4];
    s.x += b.x; s.y += b.y; s.z += b.z; s.w += b.w;
  }
  float4 av = ((const float4*)addv)[idx];
  s.x += av.x; s.y += av.y; s.z += av.z; s.w += av.w;
  if (mode == 0){
    ((float4*)out_m)[idx] = s;
    float4 o;
    o.x = s.x*sigm(s.x); o.y = s.y*sigm(s.y); o.z = s.z*sigm(s.z); o.w = s.w*sigm(s.w);
    ((float4*)out_h)[idx] = o;
  } else {
    float4 mm = ((const float4*)msrc)[idx];
    float4 o; float sg;
    sg = sigm(mm.x); o.x = s.x*(sg*(1.f+mm.x*(1.f-sg)));
    sg = sigm(mm.y); o.y = s.y*(sg*(1.f+mm.y*(1.f-sg)));
    sg = sigm(mm.z); o.z = s.z*(sg*(1.f+mm.z*(1.f-sg)));
    sg = sigm(mm.w); o.w = s.w*(sg*(1.f+mm.w*(1.f-sg)));
    int a = idx >> 5, f0 = (idx & 31)*4;
    int kc = f0 >> 5;
    int l = (a & 15) | (((f0 >> 3) & 3) << 4);
    size_t flat = (((size_t)(a>>4)*4 + kc)*64 + l)*8 + (f0 & 7);
    u16x4_t ob;
    ob[0] = f2bf(o.x); ob[1] = f2bf(o.y); ob[2] = f2bf(o.z); ob[3] = f2bf(o.w);
    *(u16x4_t*)(out_frag + flat) = ob;
  }
}

// ------- readout fwd + bwd: e_atom, g2 (f32 + bf16 A-frag) ------------------
__global__ __launch_bounds__(128) void k_readout(const float* __restrict__ h2,
        const float* __restrict__ m2, const float* __restrict__ Wr1,
        const float* __restrict__ Wr1T, const float* __restrict__ Wr2,
        float* __restrict__ e_at, float* __restrict__ g2,
        unsigned short* __restrict__ g2frag){
  int b = blockIdx.x * 8;
  int t = threadIdx.x;
  int lane = t & 63, wv = t >> 6;
  __shared__ float sh[128][8];
  __shared__ float sdu[128][8];
  __shared__ float red[2][8];
  #pragma unroll
  for (int r = 0; r < 8; r++) sh[t][r] = h2[(b+r)*F + t];
  __syncthreads();
  float u[8] = {0,0,0,0,0,0,0,0};
  for (int g = 0; g < 128; g++){
    float wvv = Wr1[g*F + t];
    float4 s0 = *(const float4*)&sh[g][0];
    float4 s1 = *(const float4*)&sh[g][4];
    u[0] += s0.x*wvv; u[1] += s0.y*wvv; u[2] += s0.z*wvv; u[3] += s0.w*wvv;
    u[4] += s1.x*wvv; u[5] += s1.y*wvv; u[6] += s1.z*wvv; u[7] += s1.w*wvv;
  }
  float w2 = Wr2[t];
  #pragma unroll
  for (int r = 0; r < 8; r++){
    float sg = sigm(u[r]);
    float e = u[r]*sg*w2;
    #pragma unroll
    for (int o = 1; o < 64; o <<= 1) e += __shfl_xor(e, o);
    if (lane == 0) red[wv][r] = e;
    sdu[t][r] = w2*(sg*(1.f + u[r]*(1.f - sg)));
  }
  __syncthreads();
  if (t < 8) e_at[b+t] = red[0][t] + red[1][t];
  float dh[8] = {0,0,0,0,0,0,0,0};
  for (int f = 0; f < 128; f++){
    float wvv = Wr1T[f*F + t];
    float4 s0 = *(const float4*)&sdu[f][0];
    float4 s1 = *(const float4*)&sdu[f][4];
    dh[0] += s0.x*wvv; dh[1] += s0.y*wvv; dh[2] += s0.z*wvv; dh[3] += s0.w*wvv;
    dh[4] += s1.x*wvv; dh[5] += s1.y*wvv; dh[6] += s1.z*wvv; dh[7] += s1.w*wvv;
  }
  int f = t;
  int kc = f >> 5;
  int jj = f & 7;
  #pragma unroll
  for (int r = 0; r < 8; r++){
    int a = b + r;
    float mm = m2[a*F + t];
    float sg = sigm(mm);
    float gv = dh[r]*(sg*(1.f + mm*(1.f - sg)));
    g2[a*F + t] = gv;
    int l = (a & 15) | (((f >> 3) & 3) << 4);
    size_t flat = (((size_t)(a>>4)*4 + kc)*64 + l)*8 + jj;
    g2frag[flat] = f2bf(gv);
  }
}

// ---------------- deterministic energy sum ----------------------------------
__global__ __launch_bounds__(256) void k_esum(const float* __restrict__ e_at,
        float* __restrict__ out){
  __shared__ float red[256];
  float s = 0.f;
  for (int i = threadIdx.x; i < N_ATOMS; i += 256) s += e_at[i];
  red[threadIdx.x] = s;
  __syncthreads();
  for (int o = 128; o > 0; o >>= 1){
    if (threadIdx.x < o) red[threadIdx.x] += red[threadIdx.x + o];
    __syncthreads();
  }
  if (threadIdx.x == 0) out[0] = red[0];
}

// ------- per-edge scalar, fused both layers ---------------------------------
// edge_s[a,n] = sum_k dr_k(d_an) * sum_f (dA2[a,k,f] h1[j,f] + dA1[a,k,f] h0[j,f])
__global__ __launch_bounds__(256) void k_edge(const float* __restrict__ dA1,
        const float* __restrict__ dA2, const float* __restrict__ h0,
        const float* __restrict__ h1,
        const int* __restrict__ nb_idx, const float* __restrict__ nb_d,
        const int* __restrict__ nb_cnt, float* __restrict__ edge_s){
  int a = blockIdx.x;
  int t = threadIdx.x;
  int lane = t & 63, w = t >> 6;
  __shared__ float sdr[MAXNB][8];
  __shared__ int s_j[MAXNB];
  int cnt = nb_cnt[a];
  for (int idx = t; idx < cnt*8; idx += 256){
    int n = idx >> 3, k = idx & 7;
    float d = nb_d[a*MAXNB + n];
    float dm = d - MU_STEP*(float)k;
    float G = expf(-GAMMA*dm*dm);
    float ph = POR*d;
    float env = 0.5f*(cosf(ph) + 1.0f);
    float denv = -0.5f*POR*sinf(ph);
    sdr[n][k] = G*(-2.0f*GAMMA*dm*env + denv);
  }
  for (int idx = t; idx < cnt; idx += 256) s_j[idx] = nb_idx[a*MAXNB + idx];
  float2 a1r[8], a2r[8];
  #pragma unroll
  for (int k = 0; k < 8; k++){
    a1r[k] = *(const float2*)&dA1[(size_t)a*KF + k*F + 2*lane];
    a2r[k] = *(const float2*)&dA2[(size_t)a*KF + k*F + 2*lane];
  }
  __syncthreads();
  for (int n = w; n < cnt; n += 4){
    int j = s_j[n];
    float2 h1v = *(const float2*)&h1[(size_t)j*F + 2*lane];
    float2 h0v = *(const float2*)&h0[(size_t)j*F + 2*lane];
    float part = 0.f;
    #pragma unroll
    for (int k = 0; k < 8; k++){
      float c = a2r[k].x*h1v.x + a2r[k].y*h1v.y + a1r[k].x*h0v.x + a1r[k].y*h0v.y;
      part += sdr[n][k]*c;
    }
    #pragma unroll
    for (int o = 1; o < 64; o <<= 1) part += __shfl_xor(part, o);
    if (lane == 0) edge_s[a*MAXNB + n] = part;
  }
}

// ------- force: F_a = -sum_j (s_aj + s_ja) * (pa-pj)/d ----------------------
__global__ __launch_bounds__(64) void k_force(const float* __restrict__ pos,
        const int* __restrict__ nb_idx, const float* __restrict__ nb_d,
        const int* __restrict__ nb_cnt, const float* __restrict__ edge_s,
        float* __restrict__ out){
  int a = blockIdx.x;
  int lane = threadIdx.x;
  float pax = pos[3*a], pay = pos[3*a+1], paz = pos[3*a+2];
  int cnt = nb_cnt[a];
  float fx = 0.f, fy = 0.f, fz = 0.f;
  for (int n = lane; n < cnt; n += 64){
    int j = nb_idx[a*MAXNB + n];
    float d = nb_d[a*MAXNB + n];
    float s = edge_s[a*MAXNB + n];
    int cj = nb_cnt[j];
    int lo = 0, hi = cj - 1, p = -1;
    while (lo <= hi){
      int mid = (lo + hi) >> 1;
      int v = nb_idx[j*MAXNB + mid];
      if (v == a){ p = mid; break; }
      if (v < a) lo = mid + 1; else hi = mid - 1;
    }
    float sj = (p >= 0) ? edge_s[j*MAXNB + p] : 0.0f;
    float coef = (s + sj)/d;
    float dx = pax - pos[3*j], dy = pay - pos[3*j+1], dz = paz - pos[3*j+2];
    fx -= coef*dx; fy -= coef*dy; fz -= coef*dz;
  }
  #pragma unroll
  for (int o = 1; o < 64; o <<= 1){
    fx += __shfl_xor(fx, o); fy += __shfl_xor(fy, o); fz += __shfl_xor(fz, o);
  }
  if (lane == 0){
    out[1 + 3*a + 0] = fx;
    out[1 + 3*a + 1] = fy;
    out[1 + 3*a + 2] = fz;
  }
}

extern "C" void kernel_launch(void* const* d_in, const int* in_sizes, int n_in,
                              void* d_out, int out_size, void* d_ws, size_t ws_size,
                              hipStream_t stream){
  const float* pos   = (const float*)d_in[0];
  const int*   z     = (const int*)  d_in[1];
  const float* embed = (const float*)d_in[2];
  const float* W1    = (const float*)d_in[3];
  const float* W2    = (const float*)d_in[4];
  const float* Wr1   = (const float*)d_in[5];
  const float* Wr2   = (const float*)d_in[6];
  float* out = (float*)d_out;

  float* ws = (float*)d_ws;
  float* h0   = ws;            // NF
  float* h1   = h0 + NF;
  float* h2   = h1 + NF;
  float* m1   = h2 + NF;
  float* m2   = m1 + NF;
  float* g2b  = m2 + NF;
  float* Bbuf = g2b + NF;      // NKF f32: dA2
  float* Cbuf = Bbuf + NKF;    // NKF f32: split partials / dA1
  unsigned short* Afrag = (unsigned short*)(Cbuf + NKF);  // NKF bf16
  unsigned short* Gfrag = Afrag + NKF;                    // NF bf16
  unsigned short* WF1  = Gfrag + NF;   // KFF bf16 each
  unsigned short* WF2  = WF1 + KFF;
  unsigned short* WDF2 = WF2 + KFF;
  unsigned short* WTF1 = WDF2 + KFF;
  unsigned short* WTF2 = WTF1 + KFF;
  float* Wr1T = (float*)(WTF2 + KFF);  // FF
  float* e_at = Wr1T + FF;             // N
  float* nb_d = e_at + N_ATOMS;        // N*MAXNB
  float* edge_s = nb_d + N_ATOMS*MAXNB;// N*MAXNB
  int* nb_idx = (int*)(edge_s + N_ATOMS*MAXNB); // N*MAXNB
  int* nb_cnt = nb_idx + N_ATOMS*MAXNB;         // N

  k_nb<<<N_ATOMS/4, 256, 0, stream>>>(pos, nb_idx, nb_d, nb_cnt);
  k_embed<<<NF/256, 256, 0, stream>>>(z, embed, h0);
  k_wprep<<<64, 256, 0, stream>>>(W1, W2, Wr1, WF1, WF2, WDF2, WTF1, WTF2, Wr1T);

  // forward layer 1
  k_agg<<<N_ATOMS, 256, 0, stream>>>(h0, nb_idx, nb_d, nb_cnt, Afrag);
  k_mgemm_fwd<<<dim3(64, 8), 256, 0, stream>>>(Afrag, WF1, Cbuf);
  k_reduce<<<NF4/256, 256, 0, stream>>>(Cbuf, h0, h0, m1, h1, Gfrag, 0);
  // forward layer 2
  k_agg<<<N_ATOMS, 256, 0, stream>>>(h1, nb_idx, nb_d, nb_cnt, Afrag);
  k_mgemm_fwd<<<dim3(64, 8), 256, 0, stream>>>(Afrag, WF2, Cbuf);
  k_reduce<<<NF4/256, 256, 0, stream>>>(Cbuf, h1, h1, m2, h2, Gfrag, 0);

  // readout + energy (g2 written as f32 + frag)
  k_readout<<<N_ATOMS/8, 128, 0, stream>>>(h2, m2, Wr1, Wr1T, Wr2, e_at, g2b, Gfrag);
  k_esum<<<1, 256, 0, stream>>>(e_at, out);

  // backward
  k_mgemm_bwd<<<dim3(64, 8), 256, 0, stream>>>(Gfrag, WTF2, Bbuf);        // dA2
  k_agg<<<N_ATOMS, 256, 0, stream>>>(g2b, nb_idx, nb_d, nb_cnt, Afrag);   // Agg2
  k_mgemm_fwd<<<dim3(64, 8), 256, 0, stream>>>(Afrag, WDF2, Cbuf);
  k_reduce<<<NF4/256, 256, 0, stream>>>(Cbuf, g2b, m1, m1, m1, Gfrag, 1); // g1 -> Gfrag
  k_mgemm_bwd<<<dim3(64, 8), 256, 0, stream>>>(Gfrag, WTF1, Cbuf);        // dA1
  k_edge<<<N_ATOMS, 256, 0, stream>>>(Cbuf, Bbuf, h0, h1, nb_idx, nb_d, nb_cnt, edge_s);
  k_force<<<N_ATOMS, 64, 0, stream>>>(pos, nb_idx, nb_d, nb_cnt, edge_s, out);
}